// Round 8
// baseline (378.219 us; speedup 1.0000x reference)
//
#include <hip/hip_runtime.h>
#include <hip/hip_bf16.h>
#include <math.h>

typedef __hip_bfloat16 bf16;
typedef __attribute__((ext_vector_type(8))) short short8;
typedef __attribute__((ext_vector_type(4))) float floatx4;
#define DEV __device__ __forceinline__

constexpr int BATCH = 4;
constexpr int DIM   = 256;
constexpr int C2    = 128;
constexpr int GK    = 40;     // HEADS*KS = 8*5
constexpr int HH    = 128;
constexpr int WW    = 128;
constexpr int NPIX  = HH * WW;   // 16384
constexpr int TPB   = 256;

DEV float toF(float v) { return v; }
DEV float toF(bf16 v)  { return __bfloat162float(v); }

DEV unsigned short f2bs(float f) {
  union { bf16 h; unsigned short u; } cv;
  cv.h = __float2bfloat16(f);
  return cv.u;
}
DEV float bs2f(unsigned short u) {
  union { float f; unsigned x; } c;
  c.x = ((unsigned)u) << 16;
  return c.f;
}

// load N f32 / bf16 values into float array (explicit vector widths)
template<int N>
DEV void load_f32v(const float* __restrict__ p, float* v) {
  if constexpr (N == 8) {
    const float4 a = *(const float4*)p;
    const float4 b = *(const float4*)(p + 4);
    v[0]=a.x; v[1]=a.y; v[2]=a.z; v[3]=a.w; v[4]=b.x; v[5]=b.y; v[6]=b.z; v[7]=b.w;
  } else if constexpr (N == 4) {
    const float4 a = *(const float4*)p;
    v[0]=a.x; v[1]=a.y; v[2]=a.z; v[3]=a.w;
  } else {
    const float2 a = *(const float2*)p;
    v[0]=a.x; v[1]=a.y;
  }
}
template<int N>
DEV void load_bf16v(const bf16* __restrict__ p, float* v) {
  if constexpr (N == 8) {
    const uint4 u = *(const uint4*)p;
    v[0]=bs2f(u.x & 0xffff); v[1]=bs2f(u.x >> 16);
    v[2]=bs2f(u.y & 0xffff); v[3]=bs2f(u.y >> 16);
    v[4]=bs2f(u.z & 0xffff); v[5]=bs2f(u.z >> 16);
    v[6]=bs2f(u.w & 0xffff); v[7]=bs2f(u.w >> 16);
  } else if constexpr (N == 4) {
    const uint2 u = *(const uint2*)p;
    v[0]=bs2f(u.x & 0xffff); v[1]=bs2f(u.x >> 16);
    v[2]=bs2f(u.y & 0xffff); v[3]=bs2f(u.y >> 16);
  } else {
    const unsigned u = *(const unsigned*)p;
    v[0]=bs2f(u & 0xffff); v[1]=bs2f(u >> 16);
  }
}
DEV void load8bf(const bf16* __restrict__ p, float* v) { load_bf16v<8>(p, v); }

// ==================== weight prepack: f32 -> bf16, 6 matrices concatenated ====
// dst layout: [proj_in 65536][cb1 8192][cb2 8192][hk_pw 5120][vk_pw 5120][proj_out 65536]
__global__ __launch_bounds__(TPB) void prepack_kernel(
    const float* __restrict__ w0, const float* __restrict__ w1,
    const float* __restrict__ w2, const float* __restrict__ w3,
    const float* __restrict__ w4, const float* __restrict__ w5,
    short* __restrict__ dst) {
  const int i = blockIdx.x * TPB + threadIdx.x;
  if (i >= 157696) return;
  int j = i;
  float v;
  if (j < 65536) v = w0[j];
  else if ((j -= 65536) < 8192) v = w1[j];
  else if ((j -= 8192) < 8192) v = w2[j];
  else if ((j -= 8192) < 5120) v = w3[j];
  else if ((j -= 5120) < 5120) v = w4[j];
  else { j -= 5120; v = w5[j]; }
  dst[i] = (short)f2bs(v);
}

// ==================== MFMA pointwise conv (R0-proven config) ====================
// Used only for proj_out now (K=256, GATED).
// R1-R3: occupancy/tile/pipelining perturbations all regress. R5: heavy work
// in staging blows VGPR. This shape is the local optimum for the structure.
template<int K, int O, int ACT, int GATED, typename TIN, typename TOUT>
__global__ __launch_bounds__(TPB) void pw2_kernel(
    const TIN* __restrict__ in, int in_bs,
    const short* __restrict__ wbf, const float* __restrict__ bias,
    TOUT* __restrict__ out, int out_bs,
    const bf16* __restrict__ gxc, const bf16* __restrict__ gattn,
    const float* __restrict__ gs, const float* __restrict__ gc) {
  constexpr int C8   = K / 8;        // channel octets
  constexpr int PXT  = K / 32;       // px per staging thread (8/4/2)
  constexpr int PG   = 64 / PXT;     // px groups per channel octet
  constexpr int ROWB = K * 2 + 16;   // LDS row bytes (16B pad keeps rowD%32==4)
  constexpr int WO   = (O + 63) / 64;
  __shared__ char smem[64 * ROWB];

  const int p0   = blockIdx.x * 64;
  const int b    = blockIdx.y;
  const int t    = threadIdx.x;
  const int lane = t & 63, wid = t >> 6;
  const int q    = lane >> 4, i16 = lane & 15;

  // ---------- stage 64px x K tile ----------
  {
    const int c8  = t / PG;          // 0..C8-1
    const int px0 = (t % PG) * PXT;
    float vals[8][PXT];
    float svals[PXT];
    if constexpr (GATED) {
      if (c8 < C8 / 2) load_f32v<PXT>(gs + (size_t)b * NPIX + p0 + px0, svals);
    }
#pragma unroll
    for (int j = 0; j < 8; ++j) {
      const int c = c8 * 8 + j;
      float tmp[PXT];
      if constexpr (GATED) {
        if (c < C2) {
          load_bf16v<PXT>(gxc + ((size_t)b * C2 + c) * NPIX + p0 + px0, tmp);
#pragma unroll
          for (int px = 0; px < PXT; ++px) vals[j][px] = tmp[px] * svals[px];
        } else {
          const float cg = gc[b * C2 + (c - C2)];
          load_bf16v<PXT>(gattn + ((size_t)b * C2 + (c - C2)) * NPIX + p0 + px0, tmp);
#pragma unroll
          for (int px = 0; px < PXT; ++px) vals[j][px] = tmp[px] * cg;
        }
      } else {
        const TIN* src = in + ((size_t)b * in_bs + c) * NPIX + p0 + px0;
        if constexpr (sizeof(TIN) == 4) load_f32v<PXT>((const float*)src, tmp);
        else                            load_bf16v<PXT>((const bf16*)src, tmp);
#pragma unroll
        for (int px = 0; px < PXT; ++px) vals[j][px] = tmp[px];
      }
    }
#pragma unroll
    for (int px = 0; px < PXT; ++px) {
      const int p = px0 + px;
      short8 pk;
#pragma unroll
      for (int j = 0; j < 8; ++j) pk[j] = (short)f2bs(vals[j][px]);
      const int phys = c8 ^ ((p >> 3) & 7);
      *reinterpret_cast<short8*>(smem + (size_t)p * ROWB + phys * 16) = pk;
    }
  }
  __syncthreads();

  const int o_base = wid * WO * 16;
  if (o_base >= O) return;

  floatx4 acc[WO][4];
#pragma unroll
  for (int ot = 0; ot < WO; ++ot)
#pragma unroll
    for (int nt = 0; nt < 4; ++nt)
      acc[ot][nt] = (floatx4){0.f, 0.f, 0.f, 0.f};

  for (int kc = 0; kc < K / 32; ++kc) {
    short8 afrag[WO];
#pragma unroll
    for (int ot = 0; ot < WO; ++ot) {
      int o = o_base + ot * 16 + i16;
      if (o >= O) o = O - 1;          // clamp; masked at store
      afrag[ot] = *reinterpret_cast<const short8*>(wbf + (size_t)o * K + kc * 32 + q * 8);
    }
    short8 bfrag[4];
#pragma unroll
    for (int nt = 0; nt < 4; ++nt) {
      const int n = nt * 16 + i16;
      const int phys = (kc * 4 + q) ^ ((n >> 3) & 7);
      bfrag[nt] = *reinterpret_cast<const short8*>(smem + (size_t)n * ROWB + phys * 16);
    }
#pragma unroll
    for (int ot = 0; ot < WO; ++ot)
#pragma unroll
      for (int nt = 0; nt < 4; ++nt)
        acc[ot][nt] = __builtin_amdgcn_mfma_f32_16x16x32_bf16(
            afrag[ot], bfrag[nt], acc[ot][nt], 0, 0, 0);
  }

  // epilogue: C/D layout col=lane&15, row=q*4+reg  (validated R2)
#pragma unroll
  for (int ot = 0; ot < WO; ++ot) {
#pragma unroll
    for (int reg = 0; reg < 4; ++reg) {
      const int o = o_base + ot * 16 + q * 4 + reg;
      if (o < O) {
        const float bv = bias[o];
#pragma unroll
        for (int nt = 0; nt < 4; ++nt) {
          float v = acc[ot][nt][reg] + bv;
          if (ACT == 1) v = fmaxf(v, 0.0f);
          if (ACT == 2) v = tanhf(v);
          TOUT* dst = out + ((size_t)b * out_bs + o) * NPIX + p0 + nt * 16 + i16;
          if constexpr (sizeof(TOUT) == 4) *dst = v;
          else *dst = __float2bfloat16(v);
        }
      }
    }
  }
}

// ==================== FUSED proj_in + cb1 + cb2 (R4, kept) ===================
__global__ __launch_bounds__(TPB) void pwfused_kernel(
    const float* __restrict__ x,
    const short* __restrict__ w_pi, const float* __restrict__ pib,
    const short* __restrict__ w_cb1, const float* __restrict__ cbb1,
    const short* __restrict__ w_cb2, const float* __restrict__ cbb2,
    float* __restrict__ x2out, bf16* __restrict__ xconv) {
  constexpr int ROWB  = 256 * 2 + 16;   // stage rows (K=256): 528B
  constexpr int HROWB = 128 * 2 + 16;   // x1 tile rows (K=128): 272B
  constexpr int TROWB = 64 * 2 + 16;    // t1 tile rows (K=64): 144B
  __shared__ char smem[64 * ROWB];
  __shared__ char hbuf[64 * HROWB];
  __shared__ char tbuf[64 * TROWB];

  const int p0   = blockIdx.x * 64;
  const int b    = blockIdx.y;
  const int t    = threadIdx.x;
  const int lane = t & 63, wid = t >> 6;
  const int q    = lane >> 4, i16 = lane & 15;

  // ---------- stage 64px x 256ch of x ----------
  {
    const int c8  = t / 8;           // 0..31
    const int px0 = (t % 8) * 8;
    float vals[8][8];
#pragma unroll
    for (int j = 0; j < 8; ++j) {
      const int c = c8 * 8 + j;
      load_f32v<8>(x + ((size_t)b * DIM + c) * NPIX + p0 + px0, vals[j]);
    }
#pragma unroll
    for (int px = 0; px < 8; ++px) {
      const int p = px0 + px;
      short8 pk;
#pragma unroll
      for (int j = 0; j < 8; ++j) pk[j] = (short)f2bs(vals[j][px]);
      const int phys = c8 ^ ((p >> 3) & 7);
      *reinterpret_cast<short8*>(smem + (size_t)p * ROWB + phys * 16) = pk;
    }
  }
  __syncthreads();

  // ---------- GEMM1: proj_in, O=256, each wave 64 channels ----------
  const int o_base = wid * 64;
  {
    floatx4 acc[4][4];
#pragma unroll
    for (int ot = 0; ot < 4; ++ot)
#pragma unroll
      for (int nt = 0; nt < 4; ++nt)
        acc[ot][nt] = (floatx4){0.f, 0.f, 0.f, 0.f};

    for (int kc = 0; kc < 8; ++kc) {
      short8 afrag[4];
#pragma unroll
      for (int ot = 0; ot < 4; ++ot) {
        const int o = o_base + ot * 16 + i16;
        afrag[ot] = *reinterpret_cast<const short8*>(w_pi + (size_t)o * 256 + kc * 32 + q * 8);
      }
      short8 bfrag[4];
#pragma unroll
      for (int nt = 0; nt < 4; ++nt) {
        const int n = nt * 16 + i16;
        const int phys = (kc * 4 + q) ^ ((n >> 3) & 7);
        bfrag[nt] = *reinterpret_cast<const short8*>(smem + (size_t)n * ROWB + phys * 16);
      }
#pragma unroll
      for (int ot = 0; ot < 4; ++ot)
#pragma unroll
        for (int nt = 0; nt < 4; ++nt)
          acc[ot][nt] = __builtin_amdgcn_mfma_f32_16x16x32_bf16(
              afrag[ot], bfrag[nt], acc[ot][nt], 0, 0, 0);
    }

    // epilogue1: ch>=128 -> x2 global (f32); ch<128 -> x1 LDS tile (bf16)
#pragma unroll
    for (int ot = 0; ot < 4; ++ot) {
      const int ch0 = o_base + ot * 16 + q * 4;   // 4 consecutive channels
      if (ch0 >= C2) {
#pragma unroll
        for (int reg = 0; reg < 4; ++reg) {
          const int o = ch0 + reg;
          const float bv = pib[o];
#pragma unroll
          for (int nt = 0; nt < 4; ++nt)
            x2out[((size_t)b * C2 + (o - C2)) * NPIX + p0 + nt * 16 + i16] =
                acc[ot][nt][reg] + bv;
        }
      } else {
        float bv4[4];
#pragma unroll
        for (int reg = 0; reg < 4; ++reg) bv4[reg] = pib[ch0 + reg];
#pragma unroll
        for (int nt = 0; nt < 4; ++nt) {
          const int px = nt * 16 + i16;
          ushort4 pk;
          pk.x = f2bs(acc[ot][nt][0] + bv4[0]);
          pk.y = f2bs(acc[ot][nt][1] + bv4[1]);
          pk.z = f2bs(acc[ot][nt][2] + bv4[2]);
          pk.w = f2bs(acc[ot][nt][3] + bv4[3]);
          const int phys = (ch0 >> 3) ^ ((px >> 3) & 7);
          *reinterpret_cast<ushort4*>(hbuf + (size_t)px * HROWB + phys * 16 +
                                      (ch0 & 7) * 2) = pk;
        }
      }
    }
  }
  __syncthreads();   // x1 tile complete

  // ---------- GEMM2: cb1 (K=128, O=64, relu), each wave 16 channels ----------
  {
    floatx4 acc2[4];
#pragma unroll
    for (int nt = 0; nt < 4; ++nt) acc2[nt] = (floatx4){0.f, 0.f, 0.f, 0.f};
    const int o2b = wid * 16;
    for (int kc = 0; kc < 4; ++kc) {
      const short8 afrag = *reinterpret_cast<const short8*>(
          w_cb1 + (size_t)(o2b + i16) * 128 + kc * 32 + q * 8);
      short8 bfrag[4];
#pragma unroll
      for (int nt = 0; nt < 4; ++nt) {
        const int n = nt * 16 + i16;
        const int phys = (kc * 4 + q) ^ ((n >> 3) & 7);
        bfrag[nt] = *reinterpret_cast<const short8*>(hbuf + (size_t)n * HROWB + phys * 16);
      }
#pragma unroll
      for (int nt = 0; nt < 4; ++nt)
        acc2[nt] = __builtin_amdgcn_mfma_f32_16x16x32_bf16(afrag, bfrag[nt], acc2[nt], 0, 0, 0);
    }
    // epilogue2 -> t1 tile in LDS (relu)
    const int ch0 = o2b + q * 4;
    float bv4[4];
#pragma unroll
    for (int reg = 0; reg < 4; ++reg) bv4[reg] = cbb1[ch0 + reg];
#pragma unroll
    for (int nt = 0; nt < 4; ++nt) {
      const int px = nt * 16 + i16;
      ushort4 pk;
      pk.x = f2bs(fmaxf(acc2[nt][0] + bv4[0], 0.f));
      pk.y = f2bs(fmaxf(acc2[nt][1] + bv4[1], 0.f));
      pk.z = f2bs(fmaxf(acc2[nt][2] + bv4[2], 0.f));
      pk.w = f2bs(fmaxf(acc2[nt][3] + bv4[3], 0.f));
      const int phys = (ch0 >> 3) ^ ((px >> 3) & 7);
      *reinterpret_cast<ushort4*>(tbuf + (size_t)px * TROWB + phys * 16 +
                                  (ch0 & 7) * 2) = pk;
    }
  }
  __syncthreads();   // t1 tile complete

  // ---------- GEMM3: cb2 (K=64, O=128), each wave 32 channels ----------
  {
    floatx4 acc3[2][4];
#pragma unroll
    for (int ot = 0; ot < 2; ++ot)
#pragma unroll
      for (int nt = 0; nt < 4; ++nt) acc3[ot][nt] = (floatx4){0.f, 0.f, 0.f, 0.f};
    const int o3b = wid * 32;
    for (int kc = 0; kc < 2; ++kc) {
      short8 afrag[2];
#pragma unroll
      for (int ot = 0; ot < 2; ++ot)
        afrag[ot] = *reinterpret_cast<const short8*>(
            w_cb2 + (size_t)(o3b + ot * 16 + i16) * 64 + kc * 32 + q * 8);
      short8 bfrag[4];
#pragma unroll
      for (int nt = 0; nt < 4; ++nt) {
        const int n = nt * 16 + i16;
        const int phys = (kc * 4 + q) ^ ((n >> 3) & 7);
        bfrag[nt] = *reinterpret_cast<const short8*>(tbuf + (size_t)n * TROWB + phys * 16);
      }
#pragma unroll
      for (int ot = 0; ot < 2; ++ot)
#pragma unroll
        for (int nt = 0; nt < 4; ++nt)
          acc3[ot][nt] = __builtin_amdgcn_mfma_f32_16x16x32_bf16(
              afrag[ot], bfrag[nt], acc3[ot][nt], 0, 0, 0);
    }
#pragma unroll
    for (int ot = 0; ot < 2; ++ot) {
#pragma unroll
      for (int reg = 0; reg < 4; ++reg) {
        const int o = o3b + ot * 16 + q * 4 + reg;
        const float bv = cbb2[o];
#pragma unroll
        for (int nt = 0; nt < 4; ++nt)
          xconv[((size_t)b * C2 + o) * NPIX + p0 + nt * 16 + i16] =
              __float2bfloat16(acc3[ot][nt][reg] + bv);
      }
    }
  }
}

// ==================== FUSED dw_h + hk_pw + fsa_h (R7) ========================
// Block = one (b,row). Phase 1: dw 1x7 along W from x2 row -> staged [px][ch]
// bf16 tile (pw2's proven 272B-row XOR layout). Phase 2: kh = tanh(GEMM O=40
// K=128 N=128px), all 4 waves active (32px each) -> kh LDS tile. Phase 3:
// fsa_h reading x2 (global, L2-hot: same addrs as phase 1) + kh from LDS.
// All fmaf orders / bf16 rounding points identical to the standalone kernels.
// Eliminates dwbuf round-trip (32MB), kbuf round-trip (10MB), 2 launches.
__global__ __launch_bounds__(TPB) void hkfused_kernel(
    const float* __restrict__ x2,
    const float* __restrict__ dw7, const float* __restrict__ dwb,
    const short* __restrict__ wpw, const float* __restrict__ pwb,
    bf16* __restrict__ outp) {
  constexpr int ROWB  = 128 * 2 + 16;   // dw tile: [px 128][ch 128] bf16, 272B rows
  constexpr int KROWB = 128 * 2 + 16;   // kh tile: [o 40][px 128] bf16, 272B rows
  __shared__ char dws[128 * ROWB];      // 34816 B
  __shared__ char khs[GK * KROWB];      // 10880 B

  const int row  = blockIdx.x;
  const int b    = blockIdx.y;
  const int t    = threadIdx.x;
  const int lane = t & 63, wid = t >> 6;
  const int q    = lane >> 4, i16 = lane & 15;
  const int c8   = t >> 4;              // 0..15 channel octet
  const int px0  = (t & 15) * 8;        // 0..120

  // ---- phase 1: depthwise 1x7 along W + stage ----
  {
    float vals[8][8];
#pragma unroll
    for (int j = 0; j < 8; ++j) {
      const int c = c8 * 8 + j;
      const float* xr = x2 + ((size_t)b * C2 + c) * NPIX + row * WW;
      float xs[14];
      if (px0 > 0) { const float4 L = *(const float4*)(xr + px0 - 4); xs[0]=L.y; xs[1]=L.z; xs[2]=L.w; }
      else { xs[0]=xs[1]=xs[2]=0.f; }
      { const float4 a = *(const float4*)(xr + px0);
        const float4 bq = *(const float4*)(xr + px0 + 4);
        xs[3]=a.x; xs[4]=a.y; xs[5]=a.z; xs[6]=a.w;
        xs[7]=bq.x; xs[8]=bq.y; xs[9]=bq.z; xs[10]=bq.w; }
      if (px0 < 120) { const float4 R = *(const float4*)(xr + px0 + 8); xs[11]=R.x; xs[12]=R.y; xs[13]=R.z; }
      else { xs[11]=xs[12]=xs[13]=0.f; }
      float wv[7];
#pragma unroll
      for (int k = 0; k < 7; ++k) wv[k] = dw7[c * 7 + k];
      const float bv = dwb[c];
#pragma unroll
      for (int i = 0; i < 8; ++i) {
        float a = bv;
#pragma unroll
        for (int k = 0; k < 7; ++k) a = fmaf(wv[k], xs[i + k], a);
        vals[j][i] = a;
      }
    }
#pragma unroll
    for (int i = 0; i < 8; ++i) {
      const int p = px0 + i;
      short8 pk;
#pragma unroll
      for (int j = 0; j < 8; ++j) pk[j] = (short)f2bs(vals[j][i]);
      const int phys = c8 ^ ((p >> 3) & 7);
      *reinterpret_cast<short8*>(dws + (size_t)p * ROWB + phys * 16) = pk;
    }
  }
  __syncthreads();

  // ---- phase 2: kh = tanh(W·dw + b), O=40 K=128, wave covers 32 px ----
  {
    const int n0 = wid * 32;
    floatx4 acc[3][2];
#pragma unroll
    for (int ot = 0; ot < 3; ++ot)
#pragma unroll
      for (int nt = 0; nt < 2; ++nt) acc[ot][nt] = (floatx4){0.f, 0.f, 0.f, 0.f};
    for (int kc = 0; kc < 4; ++kc) {
      short8 afrag[3];
#pragma unroll
      for (int ot = 0; ot < 3; ++ot) {
        int o = ot * 16 + i16;
        if (o >= GK) o = GK - 1;        // clamp; masked at store
        afrag[ot] = *reinterpret_cast<const short8*>(wpw + (size_t)o * 128 + kc * 32 + q * 8);
      }
      short8 bfrag[2];
#pragma unroll
      for (int nt = 0; nt < 2; ++nt) {
        const int n = n0 + nt * 16 + i16;
        const int phys = (kc * 4 + q) ^ ((n >> 3) & 7);
        bfrag[nt] = *reinterpret_cast<const short8*>(dws + (size_t)n * ROWB + phys * 16);
      }
#pragma unroll
      for (int ot = 0; ot < 3; ++ot)
#pragma unroll
        for (int nt = 0; nt < 2; ++nt)
          acc[ot][nt] = __builtin_amdgcn_mfma_f32_16x16x32_bf16(
              afrag[ot], bfrag[nt], acc[ot][nt], 0, 0, 0);
    }
#pragma unroll
    for (int ot = 0; ot < 3; ++ot) {
#pragma unroll
      for (int reg = 0; reg < 4; ++reg) {
        const int o = ot * 16 + q * 4 + reg;
        if (o < GK) {
          const float bv = pwb[o];
#pragma unroll
          for (int nt = 0; nt < 2; ++nt) {
            const int px = n0 + nt * 16 + i16;
            *reinterpret_cast<unsigned short*>(khs + (size_t)o * KROWB + px * 2) =
                f2bs(tanhf(acc[ot][nt][reg] + bv));
          }
        }
      }
    }
  }
  __syncthreads();

  // ---- phase 3: fsa_h from x2 (global, L2-hot) + kh (LDS) ----
  {
    const int g = c8 >> 1;              // head group, constant per octet
    float k5[5][8];
#pragma unroll
    for (int tp = 0; tp < 5; ++tp) {
      const short8 kv = *reinterpret_cast<const short8*>(
          khs + (size_t)(g * 5 + tp) * KROWB + px0 * 2);
#pragma unroll
      for (int i = 0; i < 8; ++i) k5[tp][i] = bs2f((unsigned short)kv[i]);
    }
#pragma unroll
    for (int j = 0; j < 8; ++j) {
      const int c = c8 * 8 + j;
      const float* xr = x2 + ((size_t)b * C2 + c) * NPIX + row * WW;
      float xs[14];
      if (px0 > 0) { const float4 L = *(const float4*)(xr + px0 - 4); xs[0]=L.y; xs[1]=L.z; xs[2]=L.w; }
      else { xs[0]=xs[1]=xs[2]=0.f; }
      { const float4 a = *(const float4*)(xr + px0);
        const float4 bq = *(const float4*)(xr + px0 + 4);
        xs[3]=a.x; xs[4]=a.y; xs[5]=a.z; xs[6]=a.w;
        xs[7]=bq.x; xs[8]=bq.y; xs[9]=bq.z; xs[10]=bq.w; }
      if (px0 < 120) { const float4 R = *(const float4*)(xr + px0 + 8); xs[11]=R.x; xs[12]=R.y; xs[13]=R.z; }
      else { xs[11]=xs[12]=xs[13]=0.f; }
      short8 o8;
#pragma unroll
      for (int i = 0; i < 8; ++i) {
        float a = 0.5f * (xs[i] + xs[i + 1]) * k5[0][i];
        a = fmaf(xs[i + 2], k5[1][i], a);
        a = fmaf(xs[i + 3], k5[2][i], a);
        a = fmaf(xs[i + 4], k5[3][i], a);
        a = fmaf(0.5f * (xs[i + 5] + xs[i + 6]), k5[4][i], a);
        o8[i] = (short)f2bs(a);
      }
      *reinterpret_cast<short8*>(outp + ((size_t)(b * C2 + c)) * NPIX + row * WW + px0) = o8;
    }
  }
}

// ==================== FUSED dw_v + vk_pw + fsa_v + at_mean (R7) ==============
// Same skeleton as hkfused; dw_v and fsa_v share the identical 7-row H-window
// of attn_h (re-read phase 3 from L2/L3; plane is 16MB, L3-resident).
// Phase 3 also accumulates per-(b,c) partial sums of rounded attn (16-lane
// shfl reduce per channel octet + atomicAdd; at_mean zero-init'd).
__global__ __launch_bounds__(TPB) void vkfused_kernel(
    const bf16* __restrict__ ah,
    const float* __restrict__ dw7, const float* __restrict__ dwb,
    const short* __restrict__ wpw, const float* __restrict__ pwb,
    bf16* __restrict__ outp, float* __restrict__ at_mean) {
  constexpr int ROWB  = 128 * 2 + 16;
  constexpr int KROWB = 128 * 2 + 16;
  __shared__ char dws[128 * ROWB];
  __shared__ char khs[GK * KROWB];

  const int row  = blockIdx.x;
  const int b    = blockIdx.y;
  const int t    = threadIdx.x;
  const int lane = t & 63, wid = t >> 6;
  const int q    = lane >> 4, i16 = lane & 15;
  const int c8   = t >> 4;
  const int px0  = (t & 15) * 8;

  // ---- phase 1: depthwise 7x1 along H + stage ----
  {
    float vals[8][8];
#pragma unroll
    for (int j = 0; j < 8; ++j) {
      const int c = c8 * 8 + j;
      const bf16* base = ah + ((size_t)b * C2 + c) * NPIX + px0;
      float r[7][8];
#pragma unroll
      for (int k = 0; k < 7; ++k) {
        const int hq = row - 3 + k;
        if (hq >= 0 && hq < HH) load8bf(base + (size_t)hq * WW, r[k]);
        else
#pragma unroll
          for (int i = 0; i < 8; ++i) r[k][i] = 0.f;
      }
      float wv[7];
#pragma unroll
      for (int k = 0; k < 7; ++k) wv[k] = dw7[c * 7 + k];
      const float bv = dwb[c];
#pragma unroll
      for (int i = 0; i < 8; ++i) {
        float a = bv;
#pragma unroll
        for (int k = 0; k < 7; ++k) a = fmaf(wv[k], r[k][i], a);
        vals[j][i] = a;
      }
    }
#pragma unroll
    for (int i = 0; i < 8; ++i) {
      const int p = px0 + i;
      short8 pk;
#pragma unroll
      for (int j = 0; j < 8; ++j) pk[j] = (short)f2bs(vals[j][i]);
      const int phys = c8 ^ ((p >> 3) & 7);
      *reinterpret_cast<short8*>(dws + (size_t)p * ROWB + phys * 16) = pk;
    }
  }
  __syncthreads();

  // ---- phase 2: kv = tanh(W·dw + b), O=40 K=128 ----
  {
    const int n0 = wid * 32;
    floatx4 acc[3][2];
#pragma unroll
    for (int ot = 0; ot < 3; ++ot)
#pragma unroll
      for (int nt = 0; nt < 2; ++nt) acc[ot][nt] = (floatx4){0.f, 0.f, 0.f, 0.f};
    for (int kc = 0; kc < 4; ++kc) {
      short8 afrag[3];
#pragma unroll
      for (int ot = 0; ot < 3; ++ot) {
        int o = ot * 16 + i16;
        if (o >= GK) o = GK - 1;
        afrag[ot] = *reinterpret_cast<const short8*>(wpw + (size_t)o * 128 + kc * 32 + q * 8);
      }
      short8 bfrag[2];
#pragma unroll
      for (int nt = 0; nt < 2; ++nt) {
        const int n = n0 + nt * 16 + i16;
        const int phys = (kc * 4 + q) ^ ((n >> 3) & 7);
        bfrag[nt] = *reinterpret_cast<const short8*>(dws + (size_t)n * ROWB + phys * 16);
      }
#pragma unroll
      for (int ot = 0; ot < 3; ++ot)
#pragma unroll
        for (int nt = 0; nt < 2; ++nt)
          acc[ot][nt] = __builtin_amdgcn_mfma_f32_16x16x32_bf16(
              afrag[ot], bfrag[nt], acc[ot][nt], 0, 0, 0);
    }
#pragma unroll
    for (int ot = 0; ot < 3; ++ot) {
#pragma unroll
      for (int reg = 0; reg < 4; ++reg) {
        const int o = ot * 16 + q * 4 + reg;
        if (o < GK) {
          const float bv = pwb[o];
#pragma unroll
          for (int nt = 0; nt < 2; ++nt) {
            const int px = n0 + nt * 16 + i16;
            *reinterpret_cast<unsigned short*>(khs + (size_t)o * KROWB + px * 2) =
                f2bs(tanhf(acc[ot][nt][reg] + bv));
          }
        }
      }
    }
  }
  __syncthreads();

  // ---- phase 3: fsa_v (same 7-row window) + per-channel mean partials ----
  {
    const int g = c8 >> 1;
    float k5[5][8];
#pragma unroll
    for (int tp = 0; tp < 5; ++tp) {
      const short8 kv = *reinterpret_cast<const short8*>(
          khs + (size_t)(g * 5 + tp) * KROWB + px0 * 2);
#pragma unroll
      for (int i = 0; i < 8; ++i) k5[tp][i] = bs2f((unsigned short)kv[i]);
    }
    float psum[8];
#pragma unroll
    for (int j = 0; j < 8; ++j) {
      const int c = c8 * 8 + j;
      const bf16* base = ah + ((size_t)b * C2 + c) * NPIX + px0;
      float r[7][8];
#pragma unroll
      for (int k = 0; k < 7; ++k) {
        const int hq = row - 3 + k;
        if (hq >= 0 && hq < HH) load8bf(base + (size_t)hq * WW, r[k]);
        else
#pragma unroll
          for (int i = 0; i < 8; ++i) r[k][i] = 0.f;
      }
      short8 o8;
      float ps = 0.0f;
#pragma unroll
      for (int i = 0; i < 8; ++i) {
        float a = 0.5f * (r[0][i] + r[1][i]) * k5[0][i];
        a = fmaf(r[2][i], k5[1][i], a);
        a = fmaf(r[3][i], k5[2][i], a);
        a = fmaf(r[4][i], k5[3][i], a);
        a = fmaf(0.5f * (r[5][i] + r[6][i]), k5[4][i], a);
        o8[i] = (short)f2bs(a);
        ps += bs2f((unsigned short)o8[i]);   // rounded value (matches ref path)
      }
      *reinterpret_cast<short8*>(outp + ((size_t)(b * C2 + c)) * NPIX + row * WW + px0) = o8;
      psum[j] = ps;
    }
    // reduce within the 16-lane px-group (same c8), then one atomic per (c)
#pragma unroll
    for (int j = 0; j < 8; ++j) {
#pragma unroll
      for (int off = 8; off > 0; off >>= 1) psum[j] += __shfl_down(psum[j], off, 16);
    }
    if ((t & 15) == 0) {
#pragma unroll
      for (int j = 0; j < 8; ++j)
        atomicAdd(&at_mean[b * C2 + c8 * 8 + j], psum[j]);
    }
  }
}

// -------------------- block reduction (result valid in thread 0)
DEV float block_reduce_sum(float v) {
#pragma unroll
  for (int off = 32; off > 0; off >>= 1) v += __shfl_down(v, off, 64);
  __shared__ float ls[TPB / 64];
  const int lane = threadIdx.x & 63;
  const int wid  = threadIdx.x >> 6;
  if (lane == 0) ls[wid] = v;
  __syncthreads();
  float s = 0.0f;
  if (threadIdx.x == 0) {
#pragma unroll
    for (int i = 0; i < TPB / 64; ++i) s += ls[i];
  }
  return s;
}

// fused xc_mean + s_sig: one pass over x_conv (at_mean arrives as raw SUM)
__global__ __launch_bounds__(TPB) void xs_kernel(const bf16* __restrict__ xc,
                                                 const float* __restrict__ at_mean,
                                                 float* __restrict__ xc_mean,
                                                 float* __restrict__ s_sig) {
  __shared__ float am[C2];
  const int b = blockIdx.y;
  if (threadIdx.x < C2) am[threadIdx.x] = at_mean[b * C2 + threadIdx.x] * (1.0f / NPIX);
  __syncthreads();
  const int p = blockIdx.x * TPB + threadIdx.x;
  const bf16* r = xc + (size_t)b * C2 * NPIX + p;
  float s = 0.0f, m = 0.0f;
#pragma unroll 4
  for (int c = 0; c < C2; ++c) {
    const float v = toF(r[(size_t)c * NPIX]);
    m += v;
    s = fmaf(am[c], v, s);
  }
  xc_mean[(size_t)b * NPIX + p] = m * (1.0f / C2);
  s_sig[(size_t)b * NPIX + p]   = 1.0f / (1.0f + expf(-s * (1.0f / C2)));
}

__global__ __launch_bounds__(TPB) void csig_kernel(const bf16* __restrict__ attn,
                                                   const float* __restrict__ xc_mean,
                                                   float* __restrict__ out) {
  const int bc = blockIdx.x;
  const int b  = bc / C2;
  const bf16* r = attn + (size_t)bc * NPIX;
  const float* m = xc_mean + (size_t)b * NPIX;
  float s = 0.0f;
  for (int i = threadIdx.x * 8; i < NPIX; i += TPB * 8) {
    float v[8], mm[8];
    load8bf(r + i, v);
    load_f32v<8>(m + i, mm);
#pragma unroll
    for (int j = 0; j < 8; ++j) s = fmaf(v[j], mm[j], s);
  }
  s = block_reduce_sum(s);
  if (threadIdx.x == 0) out[bc] = 1.0f / (1.0f + expf(-s * (1.0f / NPIX)));
}

extern "C" void kernel_launch(void* const* d_in, const int* in_sizes, int n_in,
                              void* d_out, int out_size, void* d_ws, size_t ws_size,
                              hipStream_t stream) {
  const float* x    = (const float*)d_in[0];
  const float* piw  = (const float*)d_in[1];
  const float* pib  = (const float*)d_in[2];
  const float* hkdw = (const float*)d_in[3];
  const float* hkdb = (const float*)d_in[4];
  const float* hkpw = (const float*)d_in[5];
  const float* hkpb = (const float*)d_in[6];
  const float* vkdw = (const float*)d_in[7];
  const float* vkdb = (const float*)d_in[8];
  const float* vkpw = (const float*)d_in[9];
  const float* vkpb = (const float*)d_in[10];
  const float* cbw1 = (const float*)d_in[11];
  const float* cbb1 = (const float*)d_in[12];
  const float* cbw2 = (const float*)d_in[13];
  const float* cbb2 = (const float*)d_in[14];
  const float* pow_ = (const float*)d_in[15];
  const float* pob  = (const float*)d_in[16];
  float* out = (float*)d_out;

  char* ws = (char*)d_ws;
  size_t off = 0;
  auto alloc = [&](size_t bytes) -> char* {
    char* p = ws + off;
    off += (bytes + 255) & ~(size_t)255;
    return p;
  };
  short* wpk    = (short*)alloc(157696 * 2);                       // packed bf16 weights
  float* x2buf  = (float*)alloc((size_t)BATCH * C2  * NPIX * 4);   // x2 only (f32 anchor)
  bf16*  x_conv = (bf16*) alloc((size_t)BATCH * C2  * NPIX * 2);
  bf16*  attn_h = (bf16*) alloc((size_t)BATCH * C2  * NPIX * 2);
  bf16*  attn   = (bf16*) alloc((size_t)BATCH * C2  * NPIX * 2);
  float* at_mean = (float*)alloc((size_t)BATCH * C2 * 4);
  float* xc_mean = (float*)alloc((size_t)BATCH * NPIX * 4);
  float* s_sig   = (float*)alloc((size_t)BATCH * NPIX * 4);
  float* c_sig   = (float*)alloc((size_t)BATCH * C2 * 4);

  const short* w_pi  = wpk;
  const short* w_cb1 = wpk + 65536;
  const short* w_cb2 = wpk + 73728;
  const short* w_hk  = wpk + 81920;
  const short* w_vk  = wpk + 87040;
  const short* w_po  = wpk + 92160;

  const dim3 blk(TPB);
  const dim3 gemm_grid(NPIX / 64, BATCH);
  const dim3 row_grid(HH, BATCH);          // fused row kernels: 128 x 4
  const int PT  = NPIX / TPB;

  // 0. prepack weights -> bf16; zero at_mean accumulator
  prepack_kernel<<<dim3((157696 + TPB - 1) / TPB), blk, 0, stream>>>(
      piw, cbw1, cbw2, hkpw, vkpw, pow_, wpk);
  hipMemsetAsync(at_mean, 0, (size_t)BATCH * C2 * 4, stream);
  // 1. fused proj_in + cb1 + cb2 -> x2buf (f32), x_conv (bf16)
  pwfused_kernel<<<gemm_grid, blk, 0, stream>>>(
      x, w_pi, pib, w_cb1, cbb1, w_cb2, cbb2, x2buf, x_conv);
  // 2. attn_h = fsa_h(x2, tanh(hk_pw(dw_h(x2))))  — one kernel per (b,row)
  hkfused_kernel<<<row_grid, blk, 0, stream>>>(
      x2buf, hkdw, hkdb, w_hk, hkpb, attn_h);
  // 3. attn = fsa_v(attn_h, tanh(vk_pw(dw_v(attn_h)))) + at_mean partial sums
  vkfused_kernel<<<row_grid, blk, 0, stream>>>(
      attn_h, vkdw, vkdb, w_vk, vkpb, attn, at_mean);
  // 4-5. gating
  xs_kernel<<<dim3(PT, BATCH), blk, 0, stream>>>(x_conv, at_mean, xc_mean, s_sig);
  csig_kernel<<<dim3(BATCH * C2), blk, 0, stream>>>(attn, xc_mean, c_sig);
  // 6. out = proj_out([s_sig*xc ; c_sig*attn])  — concat fused into staging
  pw2_kernel<256, 256, 0, 1, bf16, float><<<gemm_grid, blk, 0, stream>>>(
      x_conv, 0, w_po, pob, out, DIM, x_conv, attn, s_sig, c_sig);
}

// Round 9
// 289.632 us; speedup vs baseline: 1.3059x; 1.3059x over previous
//
#include <hip/hip_runtime.h>
#include <hip/hip_bf16.h>
#include <math.h>

typedef __hip_bfloat16 bf16;
typedef __attribute__((ext_vector_type(8))) short short8;
typedef __attribute__((ext_vector_type(4))) float floatx4;
#define DEV __device__ __forceinline__

constexpr int BATCH = 4;
constexpr int DIM   = 256;
constexpr int C2    = 128;
constexpr int GK    = 40;     // HEADS*KS = 8*5
constexpr int HH    = 128;
constexpr int WW    = 128;
constexpr int NPIX  = HH * WW;   // 16384
constexpr int TPB   = 256;

DEV float toF(float v) { return v; }
DEV float toF(bf16 v)  { return __bfloat162float(v); }

DEV unsigned short f2bs(float f) {
  union { bf16 h; unsigned short u; } cv;
  cv.h = __float2bfloat16(f);
  return cv.u;
}
DEV float bs2f(unsigned short u) {
  union { float f; unsigned x; } c;
  c.x = ((unsigned)u) << 16;
  return c.f;
}

// load N f32 / bf16 values into float array (explicit vector widths)
template<int N>
DEV void load_f32v(const float* __restrict__ p, float* v) {
  if constexpr (N == 8) {
    const float4 a = *(const float4*)p;
    const float4 b = *(const float4*)(p + 4);
    v[0]=a.x; v[1]=a.y; v[2]=a.z; v[3]=a.w; v[4]=b.x; v[5]=b.y; v[6]=b.z; v[7]=b.w;
  } else if constexpr (N == 4) {
    const float4 a = *(const float4*)p;
    v[0]=a.x; v[1]=a.y; v[2]=a.z; v[3]=a.w;
  } else {
    const float2 a = *(const float2*)p;
    v[0]=a.x; v[1]=a.y;
  }
}
template<int N>
DEV void load_bf16v(const bf16* __restrict__ p, float* v) {
  if constexpr (N == 8) {
    const uint4 u = *(const uint4*)p;
    v[0]=bs2f(u.x & 0xffff); v[1]=bs2f(u.x >> 16);
    v[2]=bs2f(u.y & 0xffff); v[3]=bs2f(u.y >> 16);
    v[4]=bs2f(u.z & 0xffff); v[5]=bs2f(u.z >> 16);
    v[6]=bs2f(u.w & 0xffff); v[7]=bs2f(u.w >> 16);
  } else if constexpr (N == 4) {
    const uint2 u = *(const uint2*)p;
    v[0]=bs2f(u.x & 0xffff); v[1]=bs2f(u.x >> 16);
    v[2]=bs2f(u.y & 0xffff); v[3]=bs2f(u.y >> 16);
  } else {
    const unsigned u = *(const unsigned*)p;
    v[0]=bs2f(u & 0xffff); v[1]=bs2f(u >> 16);
  }
}
DEV void load8bf(const bf16* __restrict__ p, float* v) { load_bf16v<8>(p, v); }

// ==================== weight prepack: f32 -> bf16, 6 matrices concatenated ====
// dst layout: [proj_in 65536][cb1 8192][cb2 8192][hk_pw 5120][vk_pw 5120][proj_out 65536]
__global__ __launch_bounds__(TPB) void prepack_kernel(
    const float* __restrict__ w0, const float* __restrict__ w1,
    const float* __restrict__ w2, const float* __restrict__ w3,
    const float* __restrict__ w4, const float* __restrict__ w5,
    short* __restrict__ dst) {
  const int i = blockIdx.x * TPB + threadIdx.x;
  if (i >= 157696) return;
  int j = i;
  float v;
  if (j < 65536) v = w0[j];
  else if ((j -= 65536) < 8192) v = w1[j];
  else if ((j -= 8192) < 8192) v = w2[j];
  else if ((j -= 8192) < 5120) v = w3[j];
  else if ((j -= 5120) < 5120) v = w4[j];
  else { j -= 5120; v = w5[j]; }
  dst[i] = (short)f2bs(v);
}

// ==================== MFMA pointwise conv (R0-proven config) ====================
// Used only for proj_out (K=256, GATED).
// R1-R3: occupancy/tile/pipelining perturbations all regress. R5/R8: tap-gather
// fused into phases blows VGPR (148/256). This shape is the local optimum.
template<int K, int O, int ACT, int GATED, typename TIN, typename TOUT>
__global__ __launch_bounds__(TPB) void pw2_kernel(
    const TIN* __restrict__ in, int in_bs,
    const short* __restrict__ wbf, const float* __restrict__ bias,
    TOUT* __restrict__ out, int out_bs,
    const bf16* __restrict__ gxc, const bf16* __restrict__ gattn,
    const float* __restrict__ gs, const float* __restrict__ gc) {
  constexpr int C8   = K / 8;        // channel octets
  constexpr int PXT  = K / 32;       // px per staging thread (8/4/2)
  constexpr int PG   = 64 / PXT;     // px groups per channel octet
  constexpr int ROWB = K * 2 + 16;   // LDS row bytes (16B pad keeps rowD%32==4)
  constexpr int WO   = (O + 63) / 64;
  __shared__ char smem[64 * ROWB];

  const int p0   = blockIdx.x * 64;
  const int b    = blockIdx.y;
  const int t    = threadIdx.x;
  const int lane = t & 63, wid = t >> 6;
  const int q    = lane >> 4, i16 = lane & 15;

  // ---------- stage 64px x K tile ----------
  {
    const int c8  = t / PG;          // 0..C8-1
    const int px0 = (t % PG) * PXT;
    float vals[8][PXT];
    float svals[PXT];
    if constexpr (GATED) {
      if (c8 < C8 / 2) load_f32v<PXT>(gs + (size_t)b * NPIX + p0 + px0, svals);
    }
#pragma unroll
    for (int j = 0; j < 8; ++j) {
      const int c = c8 * 8 + j;
      float tmp[PXT];
      if constexpr (GATED) {
        if (c < C2) {
          load_bf16v<PXT>(gxc + ((size_t)b * C2 + c) * NPIX + p0 + px0, tmp);
#pragma unroll
          for (int px = 0; px < PXT; ++px) vals[j][px] = tmp[px] * svals[px];
        } else {
          const float cg = gc[b * C2 + (c - C2)];
          load_bf16v<PXT>(gattn + ((size_t)b * C2 + (c - C2)) * NPIX + p0 + px0, tmp);
#pragma unroll
          for (int px = 0; px < PXT; ++px) vals[j][px] = tmp[px] * cg;
        }
      } else {
        const TIN* src = in + ((size_t)b * in_bs + c) * NPIX + p0 + px0;
        if constexpr (sizeof(TIN) == 4) load_f32v<PXT>((const float*)src, tmp);
        else                            load_bf16v<PXT>((const bf16*)src, tmp);
#pragma unroll
        for (int px = 0; px < PXT; ++px) vals[j][px] = tmp[px];
      }
    }
#pragma unroll
    for (int px = 0; px < PXT; ++px) {
      const int p = px0 + px;
      short8 pk;
#pragma unroll
      for (int j = 0; j < 8; ++j) pk[j] = (short)f2bs(vals[j][px]);
      const int phys = c8 ^ ((p >> 3) & 7);
      *reinterpret_cast<short8*>(smem + (size_t)p * ROWB + phys * 16) = pk;
    }
  }
  __syncthreads();

  const int o_base = wid * WO * 16;
  if (o_base >= O) return;

  floatx4 acc[WO][4];
#pragma unroll
  for (int ot = 0; ot < WO; ++ot)
#pragma unroll
    for (int nt = 0; nt < 4; ++nt)
      acc[ot][nt] = (floatx4){0.f, 0.f, 0.f, 0.f};

  for (int kc = 0; kc < K / 32; ++kc) {
    short8 afrag[WO];
#pragma unroll
    for (int ot = 0; ot < WO; ++ot) {
      int o = o_base + ot * 16 + i16;
      if (o >= O) o = O - 1;          // clamp; masked at store
      afrag[ot] = *reinterpret_cast<const short8*>(wbf + (size_t)o * K + kc * 32 + q * 8);
    }
    short8 bfrag[4];
#pragma unroll
    for (int nt = 0; nt < 4; ++nt) {
      const int n = nt * 16 + i16;
      const int phys = (kc * 4 + q) ^ ((n >> 3) & 7);
      bfrag[nt] = *reinterpret_cast<const short8*>(smem + (size_t)n * ROWB + phys * 16);
    }
#pragma unroll
    for (int ot = 0; ot < WO; ++ot)
#pragma unroll
      for (int nt = 0; nt < 4; ++nt)
        acc[ot][nt] = __builtin_amdgcn_mfma_f32_16x16x32_bf16(
            afrag[ot], bfrag[nt], acc[ot][nt], 0, 0, 0);
  }

  // epilogue: C/D layout col=lane&15, row=q*4+reg  (validated R2)
#pragma unroll
  for (int ot = 0; ot < WO; ++ot) {
#pragma unroll
    for (int reg = 0; reg < 4; ++reg) {
      const int o = o_base + ot * 16 + q * 4 + reg;
      if (o < O) {
        const float bv = bias[o];
#pragma unroll
        for (int nt = 0; nt < 4; ++nt) {
          float v = acc[ot][nt][reg] + bv;
          if (ACT == 1) v = fmaxf(v, 0.0f);
          if (ACT == 2) v = tanhf(v);
          TOUT* dst = out + ((size_t)b * out_bs + o) * NPIX + p0 + nt * 16 + i16;
          if constexpr (sizeof(TOUT) == 4) *dst = v;
          else *dst = __float2bfloat16(v);
        }
      }
    }
  }
}

// ==================== FUSED proj_in + cb1 + cb2 (R4, kept) ===================
__global__ __launch_bounds__(TPB) void pwfused_kernel(
    const float* __restrict__ x,
    const short* __restrict__ w_pi, const float* __restrict__ pib,
    const short* __restrict__ w_cb1, const float* __restrict__ cbb1,
    const short* __restrict__ w_cb2, const float* __restrict__ cbb2,
    float* __restrict__ x2out, bf16* __restrict__ xconv) {
  constexpr int ROWB  = 256 * 2 + 16;   // stage rows (K=256): 528B
  constexpr int HROWB = 128 * 2 + 16;   // x1 tile rows (K=128): 272B
  constexpr int TROWB = 64 * 2 + 16;    // t1 tile rows (K=64): 144B
  __shared__ char smem[64 * ROWB];
  __shared__ char hbuf[64 * HROWB];
  __shared__ char tbuf[64 * TROWB];

  const int p0   = blockIdx.x * 64;
  const int b    = blockIdx.y;
  const int t    = threadIdx.x;
  const int lane = t & 63, wid = t >> 6;
  const int q    = lane >> 4, i16 = lane & 15;

  // ---------- stage 64px x 256ch of x ----------
  {
    const int c8  = t / 8;           // 0..31
    const int px0 = (t % 8) * 8;
    float vals[8][8];
#pragma unroll
    for (int j = 0; j < 8; ++j) {
      const int c = c8 * 8 + j;
      load_f32v<8>(x + ((size_t)b * DIM + c) * NPIX + p0 + px0, vals[j]);
    }
#pragma unroll
    for (int px = 0; px < 8; ++px) {
      const int p = px0 + px;
      short8 pk;
#pragma unroll
      for (int j = 0; j < 8; ++j) pk[j] = (short)f2bs(vals[j][px]);
      const int phys = c8 ^ ((p >> 3) & 7);
      *reinterpret_cast<short8*>(smem + (size_t)p * ROWB + phys * 16) = pk;
    }
  }
  __syncthreads();

  // ---------- GEMM1: proj_in, O=256, each wave 64 channels ----------
  const int o_base = wid * 64;
  {
    floatx4 acc[4][4];
#pragma unroll
    for (int ot = 0; ot < 4; ++ot)
#pragma unroll
      for (int nt = 0; nt < 4; ++nt)
        acc[ot][nt] = (floatx4){0.f, 0.f, 0.f, 0.f};

    for (int kc = 0; kc < 8; ++kc) {
      short8 afrag[4];
#pragma unroll
      for (int ot = 0; ot < 4; ++ot) {
        const int o = o_base + ot * 16 + i16;
        afrag[ot] = *reinterpret_cast<const short8*>(w_pi + (size_t)o * 256 + kc * 32 + q * 8);
      }
      short8 bfrag[4];
#pragma unroll
      for (int nt = 0; nt < 4; ++nt) {
        const int n = nt * 16 + i16;
        const int phys = (kc * 4 + q) ^ ((n >> 3) & 7);
        bfrag[nt] = *reinterpret_cast<const short8*>(smem + (size_t)n * ROWB + phys * 16);
      }
#pragma unroll
      for (int ot = 0; ot < 4; ++ot)
#pragma unroll
        for (int nt = 0; nt < 4; ++nt)
          acc[ot][nt] = __builtin_amdgcn_mfma_f32_16x16x32_bf16(
              afrag[ot], bfrag[nt], acc[ot][nt], 0, 0, 0);
    }

    // epilogue1: ch>=128 -> x2 global (f32); ch<128 -> x1 LDS tile (bf16)
#pragma unroll
    for (int ot = 0; ot < 4; ++ot) {
      const int ch0 = o_base + ot * 16 + q * 4;   // 4 consecutive channels
      if (ch0 >= C2) {
#pragma unroll
        for (int reg = 0; reg < 4; ++reg) {
          const int o = ch0 + reg;
          const float bv = pib[o];
#pragma unroll
          for (int nt = 0; nt < 4; ++nt)
            x2out[((size_t)b * C2 + (o - C2)) * NPIX + p0 + nt * 16 + i16] =
                acc[ot][nt][reg] + bv;
        }
      } else {
        float bv4[4];
#pragma unroll
        for (int reg = 0; reg < 4; ++reg) bv4[reg] = pib[ch0 + reg];
#pragma unroll
        for (int nt = 0; nt < 4; ++nt) {
          const int px = nt * 16 + i16;
          ushort4 pk;
          pk.x = f2bs(acc[ot][nt][0] + bv4[0]);
          pk.y = f2bs(acc[ot][nt][1] + bv4[1]);
          pk.z = f2bs(acc[ot][nt][2] + bv4[2]);
          pk.w = f2bs(acc[ot][nt][3] + bv4[3]);
          const int phys = (ch0 >> 3) ^ ((px >> 3) & 7);
          *reinterpret_cast<ushort4*>(hbuf + (size_t)px * HROWB + phys * 16 +
                                      (ch0 & 7) * 2) = pk;
        }
      }
    }
  }
  __syncthreads();   // x1 tile complete

  // ---------- GEMM2: cb1 (K=128, O=64, relu), each wave 16 channels ----------
  {
    floatx4 acc2[4];
#pragma unroll
    for (int nt = 0; nt < 4; ++nt) acc2[nt] = (floatx4){0.f, 0.f, 0.f, 0.f};
    const int o2b = wid * 16;
    for (int kc = 0; kc < 4; ++kc) {
      const short8 afrag = *reinterpret_cast<const short8*>(
          w_cb1 + (size_t)(o2b + i16) * 128 + kc * 32 + q * 8);
      short8 bfrag[4];
#pragma unroll
      for (int nt = 0; nt < 4; ++nt) {
        const int n = nt * 16 + i16;
        const int phys = (kc * 4 + q) ^ ((n >> 3) & 7);
        bfrag[nt] = *reinterpret_cast<const short8*>(hbuf + (size_t)n * HROWB + phys * 16);
      }
#pragma unroll
      for (int nt = 0; nt < 4; ++nt)
        acc2[nt] = __builtin_amdgcn_mfma_f32_16x16x32_bf16(afrag, bfrag[nt], acc2[nt], 0, 0, 0);
    }
    // epilogue2 -> t1 tile in LDS (relu)
    const int ch0 = o2b + q * 4;
    float bv4[4];
#pragma unroll
    for (int reg = 0; reg < 4; ++reg) bv4[reg] = cbb1[ch0 + reg];
#pragma unroll
    for (int nt = 0; nt < 4; ++nt) {
      const int px = nt * 16 + i16;
      ushort4 pk;
      pk.x = f2bs(fmaxf(acc2[nt][0] + bv4[0], 0.f));
      pk.y = f2bs(fmaxf(acc2[nt][1] + bv4[1], 0.f));
      pk.z = f2bs(fmaxf(acc2[nt][2] + bv4[2], 0.f));
      pk.w = f2bs(fmaxf(acc2[nt][3] + bv4[3], 0.f));
      const int phys = (ch0 >> 3) ^ ((px >> 3) & 7);
      *reinterpret_cast<ushort4*>(tbuf + (size_t)px * TROWB + phys * 16 +
                                  (ch0 & 7) * 2) = pk;
    }
  }
  __syncthreads();   // t1 tile complete

  // ---------- GEMM3: cb2 (K=64, O=128), each wave 32 channels ----------
  {
    floatx4 acc3[2][4];
#pragma unroll
    for (int ot = 0; ot < 2; ++ot)
#pragma unroll
      for (int nt = 0; nt < 4; ++nt) acc3[ot][nt] = (floatx4){0.f, 0.f, 0.f, 0.f};
    const int o3b = wid * 32;
    for (int kc = 0; kc < 2; ++kc) {
      short8 afrag[2];
#pragma unroll
      for (int ot = 0; ot < 2; ++ot)
        afrag[ot] = *reinterpret_cast<const short8*>(
            w_cb2 + (size_t)(o3b + ot * 16 + i16) * 64 + kc * 32 + q * 8);
      short8 bfrag[4];
#pragma unroll
      for (int nt = 0; nt < 4; ++nt) {
        const int n = nt * 16 + i16;
        const int phys = (kc * 4 + q) ^ ((n >> 3) & 7);
        bfrag[nt] = *reinterpret_cast<const short8*>(tbuf + (size_t)n * TROWB + phys * 16);
      }
#pragma unroll
      for (int ot = 0; ot < 2; ++ot)
#pragma unroll
        for (int nt = 0; nt < 4; ++nt)
          acc3[ot][nt] = __builtin_amdgcn_mfma_f32_16x16x32_bf16(
              afrag[ot], bfrag[nt], acc3[ot][nt], 0, 0, 0);
    }
#pragma unroll
    for (int ot = 0; ot < 2; ++ot) {
#pragma unroll
      for (int reg = 0; reg < 4; ++reg) {
        const int o = o3b + ot * 16 + q * 4 + reg;
        const float bv = cbb2[o];
#pragma unroll
        for (int nt = 0; nt < 4; ++nt)
          xconv[((size_t)b * C2 + o) * NPIX + p0 + nt * 16 + i16] =
              __float2bfloat16(acc3[ot][nt][reg] + bv);
      }
    }
  }
}

// ==================== depthwise 1x7 along W (f32 in), 8 px/thread ============
__global__ __launch_bounds__(TPB) void dwh2_kernel(
    const float* __restrict__ in, int in_bs,
    const float* __restrict__ w7, const float* __restrict__ bias,
    bf16* __restrict__ out) {
  const int g  = blockIdx.x * TPB + threadIdx.x;
  const int w8 = g & 15;
  const int hp = (g >> 4) & (HH - 1);
  const int c  = (g >> 11) & (C2 - 1);
  const int b  = g >> 18;
  const float* xr = in + ((size_t)b * in_bs + c) * NPIX + hp * WW;
  const int px0 = w8 * 8;
  float xs[14];                       // window px0-3 .. px0+10
  if (w8 > 0) { const float4 L = *(const float4*)(xr + px0 - 4); xs[0]=L.y; xs[1]=L.z; xs[2]=L.w; }
  else { xs[0]=xs[1]=xs[2]=0.f; }
  { const float4 a = *(const float4*)(xr + px0);
    const float4 bq = *(const float4*)(xr + px0 + 4);
    xs[3]=a.x; xs[4]=a.y; xs[5]=a.z; xs[6]=a.w;
    xs[7]=bq.x; xs[8]=bq.y; xs[9]=bq.z; xs[10]=bq.w; }
  if (w8 < 15) { const float4 R = *(const float4*)(xr + px0 + 8); xs[11]=R.x; xs[12]=R.y; xs[13]=R.z; }
  else { xs[11]=xs[12]=xs[13]=0.f; }
  float wv[7];
#pragma unroll
  for (int j = 0; j < 7; ++j) wv[j] = w7[c * 7 + j];
  const float bv = bias[c];
  short8 o;
#pragma unroll
  for (int i = 0; i < 8; ++i) {
    float a = bv;
#pragma unroll
    for (int j = 0; j < 7; ++j) a = fmaf(wv[j], xs[i + j], a);
    o[i] = (short)f2bs(a);
  }
  *reinterpret_cast<short8*>(out + ((size_t)(b * C2 + c)) * NPIX + hp * WW + px0) = o;
}

// ==================== depthwise 7x1 along H (bf16 in), 8 px/thread ===========
__global__ __launch_bounds__(TPB) void dwv2_kernel(
    const bf16* __restrict__ in,
    const float* __restrict__ w7, const float* __restrict__ bias,
    bf16* __restrict__ out) {
  const int g  = blockIdx.x * TPB + threadIdx.x;
  const int w8 = g & 15;
  const int hp = (g >> 4) & (HH - 1);
  const int c  = (g >> 11) & (C2 - 1);
  const int b  = g >> 18;
  const int px0 = w8 * 8;
  const bf16* base = in + ((size_t)(b * C2 + c)) * NPIX + px0;
  float r[7][8];
#pragma unroll
  for (int j = 0; j < 7; ++j) {
    const int hq = hp - 3 + j;
    if (hq >= 0 && hq < HH) load8bf(base + (size_t)hq * WW, r[j]);
    else
#pragma unroll
      for (int i = 0; i < 8; ++i) r[j][i] = 0.f;
  }
  float wv[7];
#pragma unroll
  for (int j = 0; j < 7; ++j) wv[j] = w7[c * 7 + j];
  const float bv = bias[c];
  short8 o;
#pragma unroll
  for (int i = 0; i < 8; ++i) {
    float a = bv;
#pragma unroll
    for (int j = 0; j < 7; ++j) a = fmaf(wv[j], r[j][i], a);
    o[i] = (short)f2bs(a);
  }
  *reinterpret_cast<short8*>(out + ((size_t)(b * C2 + c)) * NPIX + hp * WW + px0) = o;
}

// ==================== FUSED hk_pw GEMM + fsa_h (R9) ==========================
// Per 64-px tile: phase A = pw2's verbatim K=128 staging from dwbuf (32 regs);
// phase B = pw2's verbatim O=40 GEMM, tanh epilogue -> kh LDS (waves 0-2);
// phase C = fsah2 verbatim, 4 channel-iterations, kh from LDS.
// Removes the pw2<128,40> dispatch + kbuf round-trip. All fmaf orders and
// bf16 rounding points identical to the R6-verified standalone kernels.
__global__ __launch_bounds__(TPB) void fsahk_kernel(
    const bf16* __restrict__ dwin,        // dwbuf
    const float* __restrict__ x2,
    const short* __restrict__ wpw, const float* __restrict__ pwb,
    bf16* __restrict__ outp) {
  constexpr int ROWB = 128 * 2 + 16;      // 272B stage rows
  constexpr int KROW = 64 * 2 + 16;       // 144B kh rows [o][px 64]
  __shared__ char smem[64 * ROWB];        // 17408
  __shared__ char khs[GK * KROW];         // 5760

  const int p0   = blockIdx.x * 64;
  const int b    = blockIdx.y;
  const int t    = threadIdx.x;
  const int lane = t & 63, wid = t >> 6;
  const int q    = lane >> 4, i16 = lane & 15;

  // ---- phase A: stage 64px x 128ch from dwbuf (pw2 K=128 staging) ----
  {
    const int c8  = t / 16;               // 0..15
    const int pxs = (t % 16) * 4;
    float vals[8][4];
#pragma unroll
    for (int j = 0; j < 8; ++j)
      load_bf16v<4>(dwin + ((size_t)b * C2 + c8 * 8 + j) * NPIX + p0 + pxs, vals[j]);
#pragma unroll
    for (int px = 0; px < 4; ++px) {
      const int p = pxs + px;
      short8 pk;
#pragma unroll
      for (int j = 0; j < 8; ++j) pk[j] = (short)f2bs(vals[j][px]);
      const int phys = c8 ^ ((p >> 3) & 7);
      *reinterpret_cast<short8*>(smem + (size_t)p * ROWB + phys * 16) = pk;
    }
  }
  __syncthreads();

  // ---- phase B: GEMM O=40 K=128 (pw2 verbatim), tanh -> khs ----
  if (wid * 16 < GK) {                    // waves 0..2
    const int o_base = wid * 16;
    floatx4 acc[4];
#pragma unroll
    for (int nt = 0; nt < 4; ++nt) acc[nt] = (floatx4){0.f, 0.f, 0.f, 0.f};
    for (int kc = 0; kc < 4; ++kc) {
      int o = o_base + i16;
      if (o >= GK) o = GK - 1;            // clamp; masked at store
      const short8 afrag = *reinterpret_cast<const short8*>(
          wpw + (size_t)o * 128 + kc * 32 + q * 8);
      short8 bfrag[4];
#pragma unroll
      for (int nt = 0; nt < 4; ++nt) {
        const int n = nt * 16 + i16;
        const int phys = (kc * 4 + q) ^ ((n >> 3) & 7);
        bfrag[nt] = *reinterpret_cast<const short8*>(smem + (size_t)n * ROWB + phys * 16);
      }
#pragma unroll
      for (int nt = 0; nt < 4; ++nt)
        acc[nt] = __builtin_amdgcn_mfma_f32_16x16x32_bf16(afrag, bfrag[nt], acc[nt], 0, 0, 0);
    }
#pragma unroll
    for (int reg = 0; reg < 4; ++reg) {
      const int o = o_base + q * 4 + reg;
      if (o < GK) {
        const float bv = pwb[o];
#pragma unroll
        for (int nt = 0; nt < 4; ++nt) {
          const int px = nt * 16 + i16;
          *reinterpret_cast<unsigned short*>(khs + (size_t)o * KROW + px * 2) =
              f2bs(tanhf(acc[nt][reg] + bv));
        }
      }
    }
  }
  __syncthreads();

  // ---- phase C: fsa_h (fsah2 verbatim), 4 channel-iterations ----
  const int row   = p0 >> 7;
  const int wbase = p0 & (WW - 1);
#pragma unroll
  for (int iter = 0; iter < 4; ++iter) {
    const int unit = iter * 256 + t;
    const int c    = unit >> 3;           // 0..127
    const int pxl  = (unit & 7) * 8;      // 0..56 within tile
    const int wpos = wbase + pxl;         // within-row pixel
    const float* xr = x2 + ((size_t)b * C2 + c) * NPIX + row * WW;
    float xs[14];
    if (wpos > 0) { const float4 L = *(const float4*)(xr + wpos - 4); xs[0]=L.y; xs[1]=L.z; xs[2]=L.w; }
    else { xs[0]=xs[1]=xs[2]=0.f; }
    { const float4 a = *(const float4*)(xr + wpos);
      const float4 bq = *(const float4*)(xr + wpos + 4);
      xs[3]=a.x; xs[4]=a.y; xs[5]=a.z; xs[6]=a.w;
      xs[7]=bq.x; xs[8]=bq.y; xs[9]=bq.z; xs[10]=bq.w; }
    if (wpos < 120) { const float4 R = *(const float4*)(xr + wpos + 8); xs[11]=R.x; xs[12]=R.y; xs[13]=R.z; }
    else { xs[11]=xs[12]=xs[13]=0.f; }
    float k5[5][8];
    const int gg = c >> 4;
#pragma unroll
    for (int tp = 0; tp < 5; ++tp) {
      const short8 kv = *reinterpret_cast<const short8*>(
          khs + (size_t)(gg * 5 + tp) * KROW + pxl * 2);
#pragma unroll
      for (int i = 0; i < 8; ++i) k5[tp][i] = bs2f((unsigned short)kv[i]);
    }
    short8 o8;
#pragma unroll
    for (int i = 0; i < 8; ++i) {
      float a = 0.5f * (xs[i] + xs[i + 1]) * k5[0][i];
      a = fmaf(xs[i + 2], k5[1][i], a);
      a = fmaf(xs[i + 3], k5[2][i], a);
      a = fmaf(xs[i + 4], k5[3][i], a);
      a = fmaf(0.5f * (xs[i + 5] + xs[i + 6]), k5[4][i], a);
      o8[i] = (short)f2bs(a);
    }
    *reinterpret_cast<short8*>(outp + ((size_t)(b * C2 + c)) * NPIX + p0 + pxl) = o8;
  }
}

// ==================== FUSED vk_pw GEMM + fsa_v + at_mean (R9) ================
// Same skeleton; phase C = fsav2 verbatim with 7-row H-window loads from
// attn_h, per-(b,c) rounded-sum partials via width-8 shfl + atomicAdd.
__global__ __launch_bounds__(TPB) void fsavk_kernel(
    const bf16* __restrict__ dwin,        // dwbuf (dw_v output)
    const bf16* __restrict__ ah,          // attn_h
    const short* __restrict__ wpw, const float* __restrict__ pwb,
    bf16* __restrict__ outp, float* __restrict__ at_mean) {
  constexpr int ROWB = 128 * 2 + 16;
  constexpr int KROW = 64 * 2 + 16;
  __shared__ char smem[64 * ROWB];
  __shared__ char khs[GK * KROW];

  const int p0   = blockIdx.x * 64;
  const int b    = blockIdx.y;
  const int t    = threadIdx.x;
  const int lane = t & 63, wid = t >> 6;
  const int q    = lane >> 4, i16 = lane & 15;

  // ---- phase A: stage 64px x 128ch from dwbuf ----
  {
    const int c8  = t / 16;
    const int pxs = (t % 16) * 4;
    float vals[8][4];
#pragma unroll
    for (int j = 0; j < 8; ++j)
      load_bf16v<4>(dwin + ((size_t)b * C2 + c8 * 8 + j) * NPIX + p0 + pxs, vals[j]);
#pragma unroll
    for (int px = 0; px < 4; ++px) {
      const int p = pxs + px;
      short8 pk;
#pragma unroll
      for (int j = 0; j < 8; ++j) pk[j] = (short)f2bs(vals[j][px]);
      const int phys = c8 ^ ((p >> 3) & 7);
      *reinterpret_cast<short8*>(smem + (size_t)p * ROWB + phys * 16) = pk;
    }
  }
  __syncthreads();

  // ---- phase B: GEMM O=40 K=128, tanh -> khs ----
  if (wid * 16 < GK) {
    const int o_base = wid * 16;
    floatx4 acc[4];
#pragma unroll
    for (int nt = 0; nt < 4; ++nt) acc[nt] = (floatx4){0.f, 0.f, 0.f, 0.f};
    for (int kc = 0; kc < 4; ++kc) {
      int o = o_base + i16;
      if (o >= GK) o = GK - 1;
      const short8 afrag = *reinterpret_cast<const short8*>(
          wpw + (size_t)o * 128 + kc * 32 + q * 8);
      short8 bfrag[4];
#pragma unroll
      for (int nt = 0; nt < 4; ++nt) {
        const int n = nt * 16 + i16;
        const int phys = (kc * 4 + q) ^ ((n >> 3) & 7);
        bfrag[nt] = *reinterpret_cast<const short8*>(smem + (size_t)n * ROWB + phys * 16);
      }
#pragma unroll
      for (int nt = 0; nt < 4; ++nt)
        acc[nt] = __builtin_amdgcn_mfma_f32_16x16x32_bf16(afrag, bfrag[nt], acc[nt], 0, 0, 0);
    }
#pragma unroll
    for (int reg = 0; reg < 4; ++reg) {
      const int o = o_base + q * 4 + reg;
      if (o < GK) {
        const float bv = pwb[o];
#pragma unroll
        for (int nt = 0; nt < 4; ++nt) {
          const int px = nt * 16 + i16;
          *reinterpret_cast<unsigned short*>(khs + (size_t)o * KROW + px * 2) =
              f2bs(tanhf(acc[nt][reg] + bv));
        }
      }
    }
  }
  __syncthreads();

  // ---- phase C: fsa_v (fsav2 verbatim) + mean partials ----
  const int row   = p0 >> 7;
  const int wbase = p0 & (WW - 1);
#pragma unroll
  for (int iter = 0; iter < 4; ++iter) {
    const int unit = iter * 256 + t;
    const int c    = unit >> 3;
    const int pxl  = (unit & 7) * 8;
    const int wpos = wbase + pxl;
    const bf16* base = ah + ((size_t)b * C2 + c) * NPIX + wpos;
    float r[7][8];
#pragma unroll
    for (int k = 0; k < 7; ++k) {
      const int hq = row - 3 + k;
      if (hq >= 0 && hq < HH) load8bf(base + (size_t)hq * WW, r[k]);
      else
#pragma unroll
        for (int i = 0; i < 8; ++i) r[k][i] = 0.f;
    }
    float k5[5][8];
    const int gg = c >> 4;
#pragma unroll
    for (int tp = 0; tp < 5; ++tp) {
      const short8 kv = *reinterpret_cast<const short8*>(
          khs + (size_t)(gg * 5 + tp) * KROW + pxl * 2);
#pragma unroll
      for (int i = 0; i < 8; ++i) k5[tp][i] = bs2f((unsigned short)kv[i]);
    }
    short8 o8;
    float ps = 0.0f;
#pragma unroll
    for (int i = 0; i < 8; ++i) {
      float a = 0.5f * (r[0][i] + r[1][i]) * k5[0][i];
      a = fmaf(r[2][i], k5[1][i], a);
      a = fmaf(r[3][i], k5[2][i], a);
      a = fmaf(r[4][i], k5[3][i], a);
      a = fmaf(0.5f * (r[5][i] + r[6][i]), k5[4][i], a);
      o8[i] = (short)f2bs(a);
      ps += bs2f((unsigned short)o8[i]);   // rounded value (matches ref path)
    }
    *reinterpret_cast<short8*>(outp + ((size_t)(b * C2 + c)) * NPIX + p0 + pxl) = o8;
    // width-8 reduce (threads sharing c) then one atomic per (b,c) per iter
#pragma unroll
    for (int off = 4; off > 0; off >>= 1) ps += __shfl_down(ps, off, 8);
    if ((t & 7) == 0) atomicAdd(&at_mean[b * C2 + c], ps);
  }
}

// -------------------- block reduction (result valid in thread 0)
DEV float block_reduce_sum(float v) {
#pragma unroll
  for (int off = 32; off > 0; off >>= 1) v += __shfl_down(v, off, 64);
  __shared__ float ls[TPB / 64];
  const int lane = threadIdx.x & 63;
  const int wid  = threadIdx.x >> 6;
  if (lane == 0) ls[wid] = v;
  __syncthreads();
  float s = 0.0f;
  if (threadIdx.x == 0) {
#pragma unroll
    for (int i = 0; i < TPB / 64; ++i) s += ls[i];
  }
  return s;
}

// fused xc_mean + s_sig: one pass over x_conv (at_mean arrives as raw SUM)
__global__ __launch_bounds__(TPB) void xs_kernel(const bf16* __restrict__ xc,
                                                 const float* __restrict__ at_mean,
                                                 float* __restrict__ xc_mean,
                                                 float* __restrict__ s_sig) {
  __shared__ float am[C2];
  const int b = blockIdx.y;
  if (threadIdx.x < C2) am[threadIdx.x] = at_mean[b * C2 + threadIdx.x] * (1.0f / NPIX);
  __syncthreads();
  const int p = blockIdx.x * TPB + threadIdx.x;
  const bf16* r = xc + (size_t)b * C2 * NPIX + p;
  float s = 0.0f, m = 0.0f;
#pragma unroll 4
  for (int c = 0; c < C2; ++c) {
    const float v = toF(r[(size_t)c * NPIX]);
    m += v;
    s = fmaf(am[c], v, s);
  }
  xc_mean[(size_t)b * NPIX + p] = m * (1.0f / C2);
  s_sig[(size_t)b * NPIX + p]   = 1.0f / (1.0f + expf(-s * (1.0f / C2)));
}

__global__ __launch_bounds__(TPB) void csig_kernel(const bf16* __restrict__ attn,
                                                   const float* __restrict__ xc_mean,
                                                   float* __restrict__ out) {
  const int bc = blockIdx.x;
  const int b  = bc / C2;
  const bf16* r = attn + (size_t)bc * NPIX;
  const float* m = xc_mean + (size_t)b * NPIX;
  float s = 0.0f;
  for (int i = threadIdx.x * 8; i < NPIX; i += TPB * 8) {
    float v[8], mm[8];
    load8bf(r + i, v);
    load_f32v<8>(m + i, mm);
#pragma unroll
    for (int j = 0; j < 8; ++j) s = fmaf(v[j], mm[j], s);
  }
  s = block_reduce_sum(s);
  if (threadIdx.x == 0) out[bc] = 1.0f / (1.0f + expf(-s * (1.0f / NPIX)));
}

extern "C" void kernel_launch(void* const* d_in, const int* in_sizes, int n_in,
                              void* d_out, int out_size, void* d_ws, size_t ws_size,
                              hipStream_t stream) {
  const float* x    = (const float*)d_in[0];
  const float* piw  = (const float*)d_in[1];
  const float* pib  = (const float*)d_in[2];
  const float* hkdw = (const float*)d_in[3];
  const float* hkdb = (const float*)d_in[4];
  const float* hkpw = (const float*)d_in[5];
  const float* hkpb = (const float*)d_in[6];
  const float* vkdw = (const float*)d_in[7];
  const float* vkdb = (const float*)d_in[8];
  const float* vkpw = (const float*)d_in[9];
  const float* vkpb = (const float*)d_in[10];
  const float* cbw1 = (const float*)d_in[11];
  const float* cbb1 = (const float*)d_in[12];
  const float* cbw2 = (const float*)d_in[13];
  const float* cbb2 = (const float*)d_in[14];
  const float* pow_ = (const float*)d_in[15];
  const float* pob  = (const float*)d_in[16];
  float* out = (float*)d_out;

  char* ws = (char*)d_ws;
  size_t off = 0;
  auto alloc = [&](size_t bytes) -> char* {
    char* p = ws + off;
    off += (bytes + 255) & ~(size_t)255;
    return p;
  };
  short* wpk    = (short*)alloc(157696 * 2);                       // packed bf16 weights
  float* x2buf  = (float*)alloc((size_t)BATCH * C2  * NPIX * 4);   // x2 only (f32 anchor)
  bf16*  x_conv = (bf16*) alloc((size_t)BATCH * C2  * NPIX * 2);
  bf16*  dwbuf  = (bf16*) alloc((size_t)BATCH * C2  * NPIX * 2);
  bf16*  attn_h = (bf16*) alloc((size_t)BATCH * C2  * NPIX * 2);
  bf16*  attn   = (bf16*) alloc((size_t)BATCH * C2  * NPIX * 2);
  float* at_mean = (float*)alloc((size_t)BATCH * C2 * 4);
  float* xc_mean = (float*)alloc((size_t)BATCH * NPIX * 4);
  float* s_sig   = (float*)alloc((size_t)BATCH * NPIX * 4);
  float* c_sig   = (float*)alloc((size_t)BATCH * C2 * 4);

  const short* w_pi  = wpk;
  const short* w_cb1 = wpk + 65536;
  const short* w_cb2 = wpk + 73728;
  const short* w_hk  = wpk + 81920;
  const short* w_vk  = wpk + 87040;
  const short* w_po  = wpk + 92160;

  const dim3 blk(TPB);
  const dim3 gemm_grid(NPIX / 64, BATCH);
  const int PT  = NPIX / TPB;
  const int EL8 = BATCH * C2 * HH * 16 / TPB;   // 8px/thread elementwise blocks

  // 0. prepack weights -> bf16; zero at_mean accumulator
  prepack_kernel<<<dim3((157696 + TPB - 1) / TPB), blk, 0, stream>>>(
      piw, cbw1, cbw2, hkpw, vkpw, pow_, wpk);
  hipMemsetAsync(at_mean, 0, (size_t)BATCH * C2 * 4, stream);
  // 1. fused proj_in + cb1 + cb2 -> x2buf (f32), x_conv (bf16)
  pwfused_kernel<<<gemm_grid, blk, 0, stream>>>(
      x, w_pi, pib, w_cb1, cbb1, w_cb2, cbb2, x2buf, x_conv);
  // 2. dwbuf = dw_h(x2)
  dwh2_kernel<<<dim3(EL8), blk, 0, stream>>>(x2buf, C2, hkdw, hkdb, dwbuf);
  // 3. attn_h = fsa_h(x2, tanh(hk_pw(dwbuf)))  — GEMM fused into fsa kernel
  fsahk_kernel<<<gemm_grid, blk, 0, stream>>>(
      dwbuf, x2buf, w_hk, hkpb, attn_h);
  // 4. dwbuf = dw_v(attn_h)
  dwv2_kernel<<<dim3(EL8), blk, 0, stream>>>(attn_h, vkdw, vkdb, dwbuf);
  // 5. attn = fsa_v(attn_h, tanh(vk_pw(dwbuf))) + at_mean partial sums
  fsavk_kernel<<<gemm_grid, blk, 0, stream>>>(
      dwbuf, attn_h, w_vk, vkpb, attn, at_mean);
  // 6-7. gating
  xs_kernel<<<dim3(PT, BATCH), blk, 0, stream>>>(x_conv, at_mean, xc_mean, s_sig);
  csig_kernel<<<dim3(BATCH * C2), blk, 0, stream>>>(attn, xc_mean, c_sig);
  // 8. out = proj_out([s_sig*xc ; c_sig*attn])  — concat fused into staging
  pw2_kernel<256, 256, 0, 1, bf16, float><<<gemm_grid, blk, 0, stream>>>(
      x_conv, 0, w_po, pob, out, DIM, x_conv, attn, s_sig, c_sig);
}

// Round 10
// 282.187 us; speedup vs baseline: 1.3403x; 1.0264x over previous
//
#include <hip/hip_runtime.h>
#include <hip/hip_bf16.h>
#include <math.h>

typedef __hip_bfloat16 bf16;
typedef __attribute__((ext_vector_type(8))) short short8;
typedef __attribute__((ext_vector_type(4))) float floatx4;
#define DEV __device__ __forceinline__

constexpr int BATCH = 4;
constexpr int DIM   = 256;
constexpr int C2    = 128;
constexpr int GK    = 40;     // HEADS*KS = 8*5
constexpr int HH    = 128;
constexpr int WW    = 128;
constexpr int NPIX  = HH * WW;   // 16384
constexpr int TPB   = 256;

DEV float toF(float v) { return v; }
DEV float toF(bf16 v)  { return __bfloat162float(v); }

DEV unsigned short f2bs(float f) {
  union { bf16 h; unsigned short u; } cv;
  cv.h = __float2bfloat16(f);
  return cv.u;
}
DEV float bs2f(unsigned short u) {
  union { float f; unsigned x; } c;
  c.x = ((unsigned)u) << 16;
  return c.f;
}

// load N f32 / bf16 values into float array (explicit vector widths)
template<int N>
DEV void load_f32v(const float* __restrict__ p, float* v) {
  if constexpr (N == 8) {
    const float4 a = *(const float4*)p;
    const float4 b = *(const float4*)(p + 4);
    v[0]=a.x; v[1]=a.y; v[2]=a.z; v[3]=a.w; v[4]=b.x; v[5]=b.y; v[6]=b.z; v[7]=b.w;
  } else if constexpr (N == 4) {
    const float4 a = *(const float4*)p;
    v[0]=a.x; v[1]=a.y; v[2]=a.z; v[3]=a.w;
  } else {
    const float2 a = *(const float2*)p;
    v[0]=a.x; v[1]=a.y;
  }
}
template<int N>
DEV void load_bf16v(const bf16* __restrict__ p, float* v) {
  if constexpr (N == 8) {
    const uint4 u = *(const uint4*)p;
    v[0]=bs2f(u.x & 0xffff); v[1]=bs2f(u.x >> 16);
    v[2]=bs2f(u.y & 0xffff); v[3]=bs2f(u.y >> 16);
    v[4]=bs2f(u.z & 0xffff); v[5]=bs2f(u.z >> 16);
    v[6]=bs2f(u.w & 0xffff); v[7]=bs2f(u.w >> 16);
  } else if constexpr (N == 4) {
    const uint2 u = *(const uint2*)p;
    v[0]=bs2f(u.x & 0xffff); v[1]=bs2f(u.x >> 16);
    v[2]=bs2f(u.y & 0xffff); v[3]=bs2f(u.y >> 16);
  } else {
    const unsigned u = *(const unsigned*)p;
    v[0]=bs2f(u & 0xffff); v[1]=bs2f(u >> 16);
  }
}
DEV void load8bf(const bf16* __restrict__ p, float* v) { load_bf16v<8>(p, v); }

// ==================== weight prepack: f32 -> bf16, 6 matrices concatenated ====
// dst layout: [proj_in 65536][cb1 8192][cb2 8192][hk_pw 5120][vk_pw 5120][proj_out 65536]
__global__ __launch_bounds__(TPB) void prepack_kernel(
    const float* __restrict__ w0, const float* __restrict__ w1,
    const float* __restrict__ w2, const float* __restrict__ w3,
    const float* __restrict__ w4, const float* __restrict__ w5,
    short* __restrict__ dst) {
  const int i = blockIdx.x * TPB + threadIdx.x;
  if (i >= 157696) return;
  int j = i;
  float v;
  if (j < 65536) v = w0[j];
  else if ((j -= 65536) < 8192) v = w1[j];
  else if ((j -= 8192) < 8192) v = w2[j];
  else if ((j -= 8192) < 5120) v = w3[j];
  else if ((j -= 5120) < 5120) v = w4[j];
  else { j -= 5120; v = w5[j]; }
  dst[i] = (short)f2bs(v);
}

// ==================== MFMA pointwise conv (R0-proven config) ====================
// Used only for proj_out (K=256, GATED).
// R1-R3: occupancy/tile/pipelining perturbations all regress. R5/R8: tap-gather
// fused into phases blows VGPR (148/256). This shape is the local optimum.
template<int K, int O, int ACT, int GATED, typename TIN, typename TOUT>
__global__ __launch_bounds__(TPB) void pw2_kernel(
    const TIN* __restrict__ in, int in_bs,
    const short* __restrict__ wbf, const float* __restrict__ bias,
    TOUT* __restrict__ out, int out_bs,
    const bf16* __restrict__ gxc, const bf16* __restrict__ gattn,
    const float* __restrict__ gs, const float* __restrict__ gc) {
  constexpr int C8   = K / 8;        // channel octets
  constexpr int PXT  = K / 32;       // px per staging thread (8/4/2)
  constexpr int PG   = 64 / PXT;     // px groups per channel octet
  constexpr int ROWB = K * 2 + 16;   // LDS row bytes (16B pad keeps rowD%32==4)
  constexpr int WO   = (O + 63) / 64;
  __shared__ char smem[64 * ROWB];

  const int p0   = blockIdx.x * 64;
  const int b    = blockIdx.y;
  const int t    = threadIdx.x;
  const int lane = t & 63, wid = t >> 6;
  const int q    = lane >> 4, i16 = lane & 15;

  // ---------- stage 64px x K tile ----------
  {
    const int c8  = t / PG;          // 0..C8-1
    const int px0 = (t % PG) * PXT;
    float vals[8][PXT];
    float svals[PXT];
    if constexpr (GATED) {
      if (c8 < C8 / 2) load_f32v<PXT>(gs + (size_t)b * NPIX + p0 + px0, svals);
    }
#pragma unroll
    for (int j = 0; j < 8; ++j) {
      const int c = c8 * 8 + j;
      float tmp[PXT];
      if constexpr (GATED) {
        if (c < C2) {
          load_bf16v<PXT>(gxc + ((size_t)b * C2 + c) * NPIX + p0 + px0, tmp);
#pragma unroll
          for (int px = 0; px < PXT; ++px) vals[j][px] = tmp[px] * svals[px];
        } else {
          const float cg = gc[b * C2 + (c - C2)];
          load_bf16v<PXT>(gattn + ((size_t)b * C2 + (c - C2)) * NPIX + p0 + px0, tmp);
#pragma unroll
          for (int px = 0; px < PXT; ++px) vals[j][px] = tmp[px] * cg;
        }
      } else {
        const TIN* src = in + ((size_t)b * in_bs + c) * NPIX + p0 + px0;
        if constexpr (sizeof(TIN) == 4) load_f32v<PXT>((const float*)src, tmp);
        else                            load_bf16v<PXT>((const bf16*)src, tmp);
#pragma unroll
        for (int px = 0; px < PXT; ++px) vals[j][px] = tmp[px];
      }
    }
#pragma unroll
    for (int px = 0; px < PXT; ++px) {
      const int p = px0 + px;
      short8 pk;
#pragma unroll
      for (int j = 0; j < 8; ++j) pk[j] = (short)f2bs(vals[j][px]);
      const int phys = c8 ^ ((p >> 3) & 7);
      *reinterpret_cast<short8*>(smem + (size_t)p * ROWB + phys * 16) = pk;
    }
  }
  __syncthreads();

  const int o_base = wid * WO * 16;
  if (o_base >= O) return;

  floatx4 acc[WO][4];
#pragma unroll
  for (int ot = 0; ot < WO; ++ot)
#pragma unroll
    for (int nt = 0; nt < 4; ++nt)
      acc[ot][nt] = (floatx4){0.f, 0.f, 0.f, 0.f};

  for (int kc = 0; kc < K / 32; ++kc) {
    short8 afrag[WO];
#pragma unroll
    for (int ot = 0; ot < WO; ++ot) {
      int o = o_base + ot * 16 + i16;
      if (o >= O) o = O - 1;          // clamp; masked at store
      afrag[ot] = *reinterpret_cast<const short8*>(wbf + (size_t)o * K + kc * 32 + q * 8);
    }
    short8 bfrag[4];
#pragma unroll
    for (int nt = 0; nt < 4; ++nt) {
      const int n = nt * 16 + i16;
      const int phys = (kc * 4 + q) ^ ((n >> 3) & 7);
      bfrag[nt] = *reinterpret_cast<const short8*>(smem + (size_t)n * ROWB + phys * 16);
    }
#pragma unroll
    for (int ot = 0; ot < WO; ++ot)
#pragma unroll
      for (int nt = 0; nt < 4; ++nt)
        acc[ot][nt] = __builtin_amdgcn_mfma_f32_16x16x32_bf16(
            afrag[ot], bfrag[nt], acc[ot][nt], 0, 0, 0);
  }

  // epilogue: C/D layout col=lane&15, row=q*4+reg  (validated R2)
#pragma unroll
  for (int ot = 0; ot < WO; ++ot) {
#pragma unroll
    for (int reg = 0; reg < 4; ++reg) {
      const int o = o_base + ot * 16 + q * 4 + reg;
      if (o < O) {
        const float bv = bias[o];
#pragma unroll
        for (int nt = 0; nt < 4; ++nt) {
          float v = acc[ot][nt][reg] + bv;
          if (ACT == 1) v = fmaxf(v, 0.0f);
          if (ACT == 2) v = tanhf(v);
          TOUT* dst = out + ((size_t)b * out_bs + o) * NPIX + p0 + nt * 16 + i16;
          if constexpr (sizeof(TOUT) == 4) *dst = v;
          else *dst = __float2bfloat16(v);
        }
      }
    }
  }
}

// ==================== FUSED proj_in + cb1 + cb2 (R4; R10: x2 out bf16) =======
__global__ __launch_bounds__(TPB) void pwfused_kernel(
    const float* __restrict__ x,
    const short* __restrict__ w_pi, const float* __restrict__ pib,
    const short* __restrict__ w_cb1, const float* __restrict__ cbb1,
    const short* __restrict__ w_cb2, const float* __restrict__ cbb2,
    bf16* __restrict__ x2out, bf16* __restrict__ xconv) {
  constexpr int ROWB  = 256 * 2 + 16;   // stage rows (K=256): 528B
  constexpr int HROWB = 128 * 2 + 16;   // x1 tile rows (K=128): 272B
  constexpr int TROWB = 64 * 2 + 16;    // t1 tile rows (K=64): 144B
  __shared__ char smem[64 * ROWB];
  __shared__ char hbuf[64 * HROWB];
  __shared__ char tbuf[64 * TROWB];

  const int p0   = blockIdx.x * 64;
  const int b    = blockIdx.y;
  const int t    = threadIdx.x;
  const int lane = t & 63, wid = t >> 6;
  const int q    = lane >> 4, i16 = lane & 15;

  // ---------- stage 64px x 256ch of x ----------
  {
    const int c8  = t / 8;           // 0..31
    const int px0 = (t % 8) * 8;
    float vals[8][8];
#pragma unroll
    for (int j = 0; j < 8; ++j) {
      const int c = c8 * 8 + j;
      load_f32v<8>(x + ((size_t)b * DIM + c) * NPIX + p0 + px0, vals[j]);
    }
#pragma unroll
    for (int px = 0; px < 8; ++px) {
      const int p = px0 + px;
      short8 pk;
#pragma unroll
      for (int j = 0; j < 8; ++j) pk[j] = (short)f2bs(vals[j][px]);
      const int phys = c8 ^ ((p >> 3) & 7);
      *reinterpret_cast<short8*>(smem + (size_t)p * ROWB + phys * 16) = pk;
    }
  }
  __syncthreads();

  // ---------- GEMM1: proj_in, O=256, each wave 64 channels ----------
  const int o_base = wid * 64;
  {
    floatx4 acc[4][4];
#pragma unroll
    for (int ot = 0; ot < 4; ++ot)
#pragma unroll
      for (int nt = 0; nt < 4; ++nt)
        acc[ot][nt] = (floatx4){0.f, 0.f, 0.f, 0.f};

    for (int kc = 0; kc < 8; ++kc) {
      short8 afrag[4];
#pragma unroll
      for (int ot = 0; ot < 4; ++ot) {
        const int o = o_base + ot * 16 + i16;
        afrag[ot] = *reinterpret_cast<const short8*>(w_pi + (size_t)o * 256 + kc * 32 + q * 8);
      }
      short8 bfrag[4];
#pragma unroll
      for (int nt = 0; nt < 4; ++nt) {
        const int n = nt * 16 + i16;
        const int phys = (kc * 4 + q) ^ ((n >> 3) & 7);
        bfrag[nt] = *reinterpret_cast<const short8*>(smem + (size_t)n * ROWB + phys * 16);
      }
#pragma unroll
      for (int ot = 0; ot < 4; ++ot)
#pragma unroll
        for (int nt = 0; nt < 4; ++nt)
          acc[ot][nt] = __builtin_amdgcn_mfma_f32_16x16x32_bf16(
              afrag[ot], bfrag[nt], acc[ot][nt], 0, 0, 0);
    }

    // epilogue1: ch>=128 -> x2 global (bf16, R10); ch<128 -> x1 LDS tile (bf16)
#pragma unroll
    for (int ot = 0; ot < 4; ++ot) {
      const int ch0 = o_base + ot * 16 + q * 4;   // 4 consecutive channels
      if (ch0 >= C2) {
#pragma unroll
        for (int reg = 0; reg < 4; ++reg) {
          const int o = ch0 + reg;
          const float bv = pib[o];
#pragma unroll
          for (int nt = 0; nt < 4; ++nt)
            x2out[((size_t)b * C2 + (o - C2)) * NPIX + p0 + nt * 16 + i16] =
                __float2bfloat16(acc[ot][nt][reg] + bv);
        }
      } else {
        float bv4[4];
#pragma unroll
        for (int reg = 0; reg < 4; ++reg) bv4[reg] = pib[ch0 + reg];
#pragma unroll
        for (int nt = 0; nt < 4; ++nt) {
          const int px = nt * 16 + i16;
          ushort4 pk;
          pk.x = f2bs(acc[ot][nt][0] + bv4[0]);
          pk.y = f2bs(acc[ot][nt][1] + bv4[1]);
          pk.z = f2bs(acc[ot][nt][2] + bv4[2]);
          pk.w = f2bs(acc[ot][nt][3] + bv4[3]);
          const int phys = (ch0 >> 3) ^ ((px >> 3) & 7);
          *reinterpret_cast<ushort4*>(hbuf + (size_t)px * HROWB + phys * 16 +
                                      (ch0 & 7) * 2) = pk;
        }
      }
    }
  }
  __syncthreads();   // x1 tile complete

  // ---------- GEMM2: cb1 (K=128, O=64, relu), each wave 16 channels ----------
  {
    floatx4 acc2[4];
#pragma unroll
    for (int nt = 0; nt < 4; ++nt) acc2[nt] = (floatx4){0.f, 0.f, 0.f, 0.f};
    const int o2b = wid * 16;
    for (int kc = 0; kc < 4; ++kc) {
      const short8 afrag = *reinterpret_cast<const short8*>(
          w_cb1 + (size_t)(o2b + i16) * 128 + kc * 32 + q * 8);
      short8 bfrag[4];
#pragma unroll
      for (int nt = 0; nt < 4; ++nt) {
        const int n = nt * 16 + i16;
        const int phys = (kc * 4 + q) ^ ((n >> 3) & 7);
        bfrag[nt] = *reinterpret_cast<const short8*>(hbuf + (size_t)n * HROWB + phys * 16);
      }
#pragma unroll
      for (int nt = 0; nt < 4; ++nt)
        acc2[nt] = __builtin_amdgcn_mfma_f32_16x16x32_bf16(afrag, bfrag[nt], acc2[nt], 0, 0, 0);
    }
    // epilogue2 -> t1 tile in LDS (relu)
    const int ch0 = o2b + q * 4;
    float bv4[4];
#pragma unroll
    for (int reg = 0; reg < 4; ++reg) bv4[reg] = cbb1[ch0 + reg];
#pragma unroll
    for (int nt = 0; nt < 4; ++nt) {
      const int px = nt * 16 + i16;
      ushort4 pk;
      pk.x = f2bs(fmaxf(acc2[nt][0] + bv4[0], 0.f));
      pk.y = f2bs(fmaxf(acc2[nt][1] + bv4[1], 0.f));
      pk.z = f2bs(fmaxf(acc2[nt][2] + bv4[2], 0.f));
      pk.w = f2bs(fmaxf(acc2[nt][3] + bv4[3], 0.f));
      const int phys = (ch0 >> 3) ^ ((px >> 3) & 7);
      *reinterpret_cast<ushort4*>(tbuf + (size_t)px * TROWB + phys * 16 +
                                  (ch0 & 7) * 2) = pk;
    }
  }
  __syncthreads();   // t1 tile complete

  // ---------- GEMM3: cb2 (K=64, O=128), each wave 32 channels ----------
  {
    floatx4 acc3[2][4];
#pragma unroll
    for (int ot = 0; ot < 2; ++ot)
#pragma unroll
      for (int nt = 0; nt < 4; ++nt) acc3[ot][nt] = (floatx4){0.f, 0.f, 0.f, 0.f};
    const int o3b = wid * 32;
    for (int kc = 0; kc < 2; ++kc) {
      short8 afrag[2];
#pragma unroll
      for (int ot = 0; ot < 2; ++ot)
        afrag[ot] = *reinterpret_cast<const short8*>(
            w_cb2 + (size_t)(o3b + ot * 16 + i16) * 64 + kc * 32 + q * 8);
      short8 bfrag[4];
#pragma unroll
      for (int nt = 0; nt < 4; ++nt) {
        const int n = nt * 16 + i16;
        const int phys = (kc * 4 + q) ^ ((n >> 3) & 7);
        bfrag[nt] = *reinterpret_cast<const short8*>(tbuf + (size_t)n * TROWB + phys * 16);
      }
#pragma unroll
      for (int ot = 0; ot < 2; ++ot)
#pragma unroll
        for (int nt = 0; nt < 4; ++nt)
          acc3[ot][nt] = __builtin_amdgcn_mfma_f32_16x16x32_bf16(
              afrag[ot], bfrag[nt], acc3[ot][nt], 0, 0, 0);
    }
#pragma unroll
    for (int ot = 0; ot < 2; ++ot) {
#pragma unroll
      for (int reg = 0; reg < 4; ++reg) {
        const int o = o3b + ot * 16 + q * 4 + reg;
        const float bv = cbb2[o];
#pragma unroll
        for (int nt = 0; nt < 4; ++nt)
          xconv[((size_t)b * C2 + o) * NPIX + p0 + nt * 16 + i16] =
              __float2bfloat16(acc3[ot][nt][reg] + bv);
      }
    }
  }
}

// ==================== depthwise 1x7 along W (bf16 in, R10), 8 px/thread ======
__global__ __launch_bounds__(TPB) void dwh2_kernel(
    const bf16* __restrict__ in,
    const float* __restrict__ w7, const float* __restrict__ bias,
    bf16* __restrict__ out) {
  const int g  = blockIdx.x * TPB + threadIdx.x;
  const int w8 = g & 15;
  const int hp = (g >> 4) & (HH - 1);
  const int c  = (g >> 11) & (C2 - 1);
  const int b  = g >> 18;
  const bf16* xr = in + ((size_t)(b * C2 + c)) * NPIX + hp * WW;
  const int px0 = w8 * 8;
  float xs[14];                       // window px0-3 .. px0+10
  if (w8 > 0) { float L[4]; load_bf16v<4>(xr + px0 - 4, L); xs[0]=L[1]; xs[1]=L[2]; xs[2]=L[3]; }
  else { xs[0]=xs[1]=xs[2]=0.f; }
  { float m[8]; load8bf(xr + px0, m);
#pragma unroll
    for (int i = 0; i < 8; ++i) xs[3 + i] = m[i]; }
  if (w8 < 15) { float R[4]; load_bf16v<4>(xr + px0 + 8, R); xs[11]=R[0]; xs[12]=R[1]; xs[13]=R[2]; }
  else { xs[11]=xs[12]=xs[13]=0.f; }
  float wv[7];
#pragma unroll
  for (int j = 0; j < 7; ++j) wv[j] = w7[c * 7 + j];
  const float bv = bias[c];
  short8 o;
#pragma unroll
  for (int i = 0; i < 8; ++i) {
    float a = bv;
#pragma unroll
    for (int j = 0; j < 7; ++j) a = fmaf(wv[j], xs[i + j], a);
    o[i] = (short)f2bs(a);
  }
  *reinterpret_cast<short8*>(out + ((size_t)(b * C2 + c)) * NPIX + hp * WW + px0) = o;
}

// ==================== depthwise 7x1 along H (bf16 in), 8 px/thread ===========
__global__ __launch_bounds__(TPB) void dwv2_kernel(
    const bf16* __restrict__ in,
    const float* __restrict__ w7, const float* __restrict__ bias,
    bf16* __restrict__ out) {
  const int g  = blockIdx.x * TPB + threadIdx.x;
  const int w8 = g & 15;
  const int hp = (g >> 4) & (HH - 1);
  const int c  = (g >> 11) & (C2 - 1);
  const int b  = g >> 18;
  const int px0 = w8 * 8;
  const bf16* base = in + ((size_t)(b * C2 + c)) * NPIX + px0;
  float r[7][8];
#pragma unroll
  for (int j = 0; j < 7; ++j) {
    const int hq = hp - 3 + j;
    if (hq >= 0 && hq < HH) load8bf(base + (size_t)hq * WW, r[j]);
    else
#pragma unroll
      for (int i = 0; i < 8; ++i) r[j][i] = 0.f;
  }
  float wv[7];
#pragma unroll
  for (int j = 0; j < 7; ++j) wv[j] = w7[c * 7 + j];
  const float bv = bias[c];
  short8 o;
#pragma unroll
  for (int i = 0; i < 8; ++i) {
    float a = bv;
#pragma unroll
    for (int j = 0; j < 7; ++j) a = fmaf(wv[j], r[j][i], a);
    o[i] = (short)f2bs(a);
  }
  *reinterpret_cast<short8*>(out + ((size_t)(b * C2 + c)) * NPIX + hp * WW + px0) = o;
}

// ==================== FUSED hk_pw GEMM + fsa_h (R9; R10: x2 bf16) ============
// Per 64-px tile: phase A = pw2's verbatim K=128 staging from dwbuf (32 regs);
// phase B = pw2's verbatim O=40 GEMM, tanh epilogue -> kh LDS (waves 0-2);
// phase C = fsah2 verbatim (bf16 x2 window loads), kh from LDS.
__global__ __launch_bounds__(TPB) void fsahk_kernel(
    const bf16* __restrict__ dwin,        // dwbuf
    const bf16* __restrict__ x2,
    const short* __restrict__ wpw, const float* __restrict__ pwb,
    bf16* __restrict__ outp) {
  constexpr int ROWB = 128 * 2 + 16;      // 272B stage rows
  constexpr int KROW = 64 * 2 + 16;       // 144B kh rows [o][px 64]
  __shared__ char smem[64 * ROWB];        // 17408
  __shared__ char khs[GK * KROW];         // 5760

  const int p0   = blockIdx.x * 64;
  const int b    = blockIdx.y;
  const int t    = threadIdx.x;
  const int lane = t & 63, wid = t >> 6;
  const int q    = lane >> 4, i16 = lane & 15;

  // ---- phase A: stage 64px x 128ch from dwbuf (pw2 K=128 staging) ----
  {
    const int c8  = t / 16;               // 0..15
    const int pxs = (t % 16) * 4;
    float vals[8][4];
#pragma unroll
    for (int j = 0; j < 8; ++j)
      load_bf16v<4>(dwin + ((size_t)b * C2 + c8 * 8 + j) * NPIX + p0 + pxs, vals[j]);
#pragma unroll
    for (int px = 0; px < 4; ++px) {
      const int p = pxs + px;
      short8 pk;
#pragma unroll
      for (int j = 0; j < 8; ++j) pk[j] = (short)f2bs(vals[j][px]);
      const int phys = c8 ^ ((p >> 3) & 7);
      *reinterpret_cast<short8*>(smem + (size_t)p * ROWB + phys * 16) = pk;
    }
  }
  __syncthreads();

  // ---- phase B: GEMM O=40 K=128 (pw2 verbatim), tanh -> khs ----
  if (wid * 16 < GK) {                    // waves 0..2
    const int o_base = wid * 16;
    floatx4 acc[4];
#pragma unroll
    for (int nt = 0; nt < 4; ++nt) acc[nt] = (floatx4){0.f, 0.f, 0.f, 0.f};
    for (int kc = 0; kc < 4; ++kc) {
      int o = o_base + i16;
      if (o >= GK) o = GK - 1;            // clamp; masked at store
      const short8 afrag = *reinterpret_cast<const short8*>(
          wpw + (size_t)o * 128 + kc * 32 + q * 8);
      short8 bfrag[4];
#pragma unroll
      for (int nt = 0; nt < 4; ++nt) {
        const int n = nt * 16 + i16;
        const int phys = (kc * 4 + q) ^ ((n >> 3) & 7);
        bfrag[nt] = *reinterpret_cast<const short8*>(smem + (size_t)n * ROWB + phys * 16);
      }
#pragma unroll
      for (int nt = 0; nt < 4; ++nt)
        acc[nt] = __builtin_amdgcn_mfma_f32_16x16x32_bf16(afrag, bfrag[nt], acc[nt], 0, 0, 0);
    }
#pragma unroll
    for (int reg = 0; reg < 4; ++reg) {
      const int o = o_base + q * 4 + reg;
      if (o < GK) {
        const float bv = pwb[o];
#pragma unroll
        for (int nt = 0; nt < 4; ++nt) {
          const int px = nt * 16 + i16;
          *reinterpret_cast<unsigned short*>(khs + (size_t)o * KROW + px * 2) =
              f2bs(tanhf(acc[nt][reg] + bv));
        }
      }
    }
  }
  __syncthreads();

  // ---- phase C: fsa_h (fsah2 verbatim, bf16 x2), 4 channel-iterations ----
  const int row   = p0 >> 7;
  const int wbase = p0 & (WW - 1);
#pragma unroll
  for (int iter = 0; iter < 4; ++iter) {
    const int unit = iter * 256 + t;
    const int c    = unit >> 3;           // 0..127
    const int pxl  = (unit & 7) * 8;      // 0..56 within tile
    const int wpos = wbase + pxl;         // within-row pixel
    const bf16* xr = x2 + ((size_t)b * C2 + c) * NPIX + row * WW;
    float xs[14];
    if (wpos > 0) { float L[4]; load_bf16v<4>(xr + wpos - 4, L); xs[0]=L[1]; xs[1]=L[2]; xs[2]=L[3]; }
    else { xs[0]=xs[1]=xs[2]=0.f; }
    { float m[8]; load8bf(xr + wpos, m);
#pragma unroll
      for (int i = 0; i < 8; ++i) xs[3 + i] = m[i]; }
    if (wpos < 120) { float R[4]; load_bf16v<4>(xr + wpos + 8, R); xs[11]=R[0]; xs[12]=R[1]; xs[13]=R[2]; }
    else { xs[11]=xs[12]=xs[13]=0.f; }
    float k5[5][8];
    const int gg = c >> 4;
#pragma unroll
    for (int tp = 0; tp < 5; ++tp) {
      const short8 kv = *reinterpret_cast<const short8*>(
          khs + (size_t)(gg * 5 + tp) * KROW + pxl * 2);
#pragma unroll
      for (int i = 0; i < 8; ++i) k5[tp][i] = bs2f((unsigned short)kv[i]);
    }
    short8 o8;
#pragma unroll
    for (int i = 0; i < 8; ++i) {
      float a = 0.5f * (xs[i] + xs[i + 1]) * k5[0][i];
      a = fmaf(xs[i + 2], k5[1][i], a);
      a = fmaf(xs[i + 3], k5[2][i], a);
      a = fmaf(xs[i + 4], k5[3][i], a);
      a = fmaf(0.5f * (xs[i + 5] + xs[i + 6]), k5[4][i], a);
      o8[i] = (short)f2bs(a);
    }
    *reinterpret_cast<short8*>(outp + ((size_t)(b * C2 + c)) * NPIX + p0 + pxl) = o8;
  }
}

// ==================== FUSED vk_pw GEMM + fsa_v + at_mean (R9) ================
// Same skeleton; phase C = fsav2 verbatim with 7-row H-window loads from
// attn_h, per-(b,c) rounded-sum partials via width-8 shfl + atomicAdd.
__global__ __launch_bounds__(TPB) void fsavk_kernel(
    const bf16* __restrict__ dwin,        // dwbuf (dw_v output)
    const bf16* __restrict__ ah,          // attn_h
    const short* __restrict__ wpw, const float* __restrict__ pwb,
    bf16* __restrict__ outp, float* __restrict__ at_mean) {
  constexpr int ROWB = 128 * 2 + 16;
  constexpr int KROW = 64 * 2 + 16;
  __shared__ char smem[64 * ROWB];
  __shared__ char khs[GK * KROW];

  const int p0   = blockIdx.x * 64;
  const int b    = blockIdx.y;
  const int t    = threadIdx.x;
  const int lane = t & 63, wid = t >> 6;
  const int q    = lane >> 4, i16 = lane & 15;

  // ---- phase A: stage 64px x 128ch from dwbuf ----
  {
    const int c8  = t / 16;
    const int pxs = (t % 16) * 4;
    float vals[8][4];
#pragma unroll
    for (int j = 0; j < 8; ++j)
      load_bf16v<4>(dwin + ((size_t)b * C2 + c8 * 8 + j) * NPIX + p0 + pxs, vals[j]);
#pragma unroll
    for (int px = 0; px < 4; ++px) {
      const int p = pxs + px;
      short8 pk;
#pragma unroll
      for (int j = 0; j < 8; ++j) pk[j] = (short)f2bs(vals[j][px]);
      const int phys = c8 ^ ((p >> 3) & 7);
      *reinterpret_cast<short8*>(smem + (size_t)p * ROWB + phys * 16) = pk;
    }
  }
  __syncthreads();

  // ---- phase B: GEMM O=40 K=128, tanh -> khs ----
  if (wid * 16 < GK) {
    const int o_base = wid * 16;
    floatx4 acc[4];
#pragma unroll
    for (int nt = 0; nt < 4; ++nt) acc[nt] = (floatx4){0.f, 0.f, 0.f, 0.f};
    for (int kc = 0; kc < 4; ++kc) {
      int o = o_base + i16;
      if (o >= GK) o = GK - 1;
      const short8 afrag = *reinterpret_cast<const short8*>(
          wpw + (size_t)o * 128 + kc * 32 + q * 8);
      short8 bfrag[4];
#pragma unroll
      for (int nt = 0; nt < 4; ++nt) {
        const int n = nt * 16 + i16;
        const int phys = (kc * 4 + q) ^ ((n >> 3) & 7);
        bfrag[nt] = *reinterpret_cast<const short8*>(smem + (size_t)n * ROWB + phys * 16);
      }
#pragma unroll
      for (int nt = 0; nt < 4; ++nt)
        acc[nt] = __builtin_amdgcn_mfma_f32_16x16x32_bf16(afrag, bfrag[nt], acc[nt], 0, 0, 0);
    }
#pragma unroll
    for (int reg = 0; reg < 4; ++reg) {
      const int o = o_base + q * 4 + reg;
      if (o < GK) {
        const float bv = pwb[o];
#pragma unroll
        for (int nt = 0; nt < 4; ++nt) {
          const int px = nt * 16 + i16;
          *reinterpret_cast<unsigned short*>(khs + (size_t)o * KROW + px * 2) =
              f2bs(tanhf(acc[nt][reg] + bv));
        }
      }
    }
  }
  __syncthreads();

  // ---- phase C: fsa_v (fsav2 verbatim) + mean partials ----
  const int row   = p0 >> 7;
  const int wbase = p0 & (WW - 1);
#pragma unroll
  for (int iter = 0; iter < 4; ++iter) {
    const int unit = iter * 256 + t;
    const int c    = unit >> 3;
    const int pxl  = (unit & 7) * 8;
    const int wpos = wbase + pxl;
    const bf16* base = ah + ((size_t)b * C2 + c) * NPIX + wpos;
    float r[7][8];
#pragma unroll
    for (int k = 0; k < 7; ++k) {
      const int hq = row - 3 + k;
      if (hq >= 0 && hq < HH) load8bf(base + (size_t)hq * WW, r[k]);
      else
#pragma unroll
        for (int i = 0; i < 8; ++i) r[k][i] = 0.f;
    }
    float k5[5][8];
    const int gg = c >> 4;
#pragma unroll
    for (int tp = 0; tp < 5; ++tp) {
      const short8 kv = *reinterpret_cast<const short8*>(
          khs + (size_t)(gg * 5 + tp) * KROW + pxl * 2);
#pragma unroll
      for (int i = 0; i < 8; ++i) k5[tp][i] = bs2f((unsigned short)kv[i]);
    }
    short8 o8;
    float ps = 0.0f;
#pragma unroll
    for (int i = 0; i < 8; ++i) {
      float a = 0.5f * (r[0][i] + r[1][i]) * k5[0][i];
      a = fmaf(r[2][i], k5[1][i], a);
      a = fmaf(r[3][i], k5[2][i], a);
      a = fmaf(r[4][i], k5[3][i], a);
      a = fmaf(0.5f * (r[5][i] + r[6][i]), k5[4][i], a);
      o8[i] = (short)f2bs(a);
      ps += bs2f((unsigned short)o8[i]);   // rounded value (matches ref path)
    }
    *reinterpret_cast<short8*>(outp + ((size_t)(b * C2 + c)) * NPIX + p0 + pxl) = o8;
    // width-8 reduce (threads sharing c) then one atomic per (b,c) per iter
#pragma unroll
    for (int off = 4; off > 0; off >>= 1) ps += __shfl_down(ps, off, 8);
    if ((t & 7) == 0) atomicAdd(&at_mean[b * C2 + c], ps);
  }
}

// -------------------- block reduction (result valid in thread 0)
DEV float block_reduce_sum(float v) {
#pragma unroll
  for (int off = 32; off > 0; off >>= 1) v += __shfl_down(v, off, 64);
  __shared__ float ls[TPB / 64];
  const int lane = threadIdx.x & 63;
  const int wid  = threadIdx.x >> 6;
  if (lane == 0) ls[wid] = v;
  __syncthreads();
  float s = 0.0f;
  if (threadIdx.x == 0) {
#pragma unroll
    for (int i = 0; i < TPB / 64; ++i) s += ls[i];
  }
  return s;
}

// fused xc_mean + s_sig: one pass over x_conv (at_mean arrives as raw SUM)
__global__ __launch_bounds__(TPB) void xs_kernel(const bf16* __restrict__ xc,
                                                 const float* __restrict__ at_mean,
                                                 float* __restrict__ xc_mean,
                                                 float* __restrict__ s_sig) {
  __shared__ float am[C2];
  const int b = blockIdx.y;
  if (threadIdx.x < C2) am[threadIdx.x] = at_mean[b * C2 + threadIdx.x] * (1.0f / NPIX);
  __syncthreads();
  const int p = blockIdx.x * TPB + threadIdx.x;
  const bf16* r = xc + (size_t)b * C2 * NPIX + p;
  float s = 0.0f, m = 0.0f;
#pragma unroll 4
  for (int c = 0; c < C2; ++c) {
    const float v = toF(r[(size_t)c * NPIX]);
    m += v;
    s = fmaf(am[c], v, s);
  }
  xc_mean[(size_t)b * NPIX + p] = m * (1.0f / C2);
  s_sig[(size_t)b * NPIX + p]   = 1.0f / (1.0f + expf(-s * (1.0f / C2)));
}

__global__ __launch_bounds__(TPB) void csig_kernel(const bf16* __restrict__ attn,
                                                   const float* __restrict__ xc_mean,
                                                   float* __restrict__ out) {
  const int bc = blockIdx.x;
  const int b  = bc / C2;
  const bf16* r = attn + (size_t)bc * NPIX;
  const float* m = xc_mean + (size_t)b * NPIX;
  float s = 0.0f;
  for (int i = threadIdx.x * 8; i < NPIX; i += TPB * 8) {
    float v[8], mm[8];
    load8bf(r + i, v);
    load_f32v<8>(m + i, mm);
#pragma unroll
    for (int j = 0; j < 8; ++j) s = fmaf(v[j], mm[j], s);
  }
  s = block_reduce_sum(s);
  if (threadIdx.x == 0) out[bc] = 1.0f / (1.0f + expf(-s * (1.0f / NPIX)));
}

extern "C" void kernel_launch(void* const* d_in, const int* in_sizes, int n_in,
                              void* d_out, int out_size, void* d_ws, size_t ws_size,
                              hipStream_t stream) {
  const float* x    = (const float*)d_in[0];
  const float* piw  = (const float*)d_in[1];
  const float* pib  = (const float*)d_in[2];
  const float* hkdw = (const float*)d_in[3];
  const float* hkdb = (const float*)d_in[4];
  const float* hkpw = (const float*)d_in[5];
  const float* hkpb = (const float*)d_in[6];
  const float* vkdw = (const float*)d_in[7];
  const float* vkdb = (const float*)d_in[8];
  const float* vkpw = (const float*)d_in[9];
  const float* vkpb = (const float*)d_in[10];
  const float* cbw1 = (const float*)d_in[11];
  const float* cbb1 = (const float*)d_in[12];
  const float* cbw2 = (const float*)d_in[13];
  const float* cbb2 = (const float*)d_in[14];
  const float* pow_ = (const float*)d_in[15];
  const float* pob  = (const float*)d_in[16];
  float* out = (float*)d_out;

  char* ws = (char*)d_ws;
  size_t off = 0;
  auto alloc = [&](size_t bytes) -> char* {
    char* p = ws + off;
    off += (bytes + 255) & ~(size_t)255;
    return p;
  };
  short* wpk    = (short*)alloc(157696 * 2);                       // packed bf16 weights
  bf16*  x2buf  = (bf16*) alloc((size_t)BATCH * C2  * NPIX * 2);   // x2 bf16 (R10)
  bf16*  x_conv = (bf16*) alloc((size_t)BATCH * C2  * NPIX * 2);
  bf16*  dwbuf  = (bf16*) alloc((size_t)BATCH * C2  * NPIX * 2);
  bf16*  attn_h = (bf16*) alloc((size_t)BATCH * C2  * NPIX * 2);
  bf16*  attn   = (bf16*) alloc((size_t)BATCH * C2  * NPIX * 2);
  float* at_mean = (float*)alloc((size_t)BATCH * C2 * 4);
  float* xc_mean = (float*)alloc((size_t)BATCH * NPIX * 4);
  float* s_sig   = (float*)alloc((size_t)BATCH * NPIX * 4);
  float* c_sig   = (float*)alloc((size_t)BATCH * C2 * 4);

  const short* w_pi  = wpk;
  const short* w_cb1 = wpk + 65536;
  const short* w_cb2 = wpk + 73728;
  const short* w_hk  = wpk + 81920;
  const short* w_vk  = wpk + 87040;
  const short* w_po  = wpk + 92160;

  const dim3 blk(TPB);
  const dim3 gemm_grid(NPIX / 64, BATCH);
  const int PT  = NPIX / TPB;
  const int EL8 = BATCH * C2 * HH * 16 / TPB;   // 8px/thread elementwise blocks

  // 0. prepack weights -> bf16; zero at_mean accumulator
  prepack_kernel<<<dim3((157696 + TPB - 1) / TPB), blk, 0, stream>>>(
      piw, cbw1, cbw2, hkpw, vkpw, pow_, wpk);
  hipMemsetAsync(at_mean, 0, (size_t)BATCH * C2 * 4, stream);
  // 1. fused proj_in + cb1 + cb2 -> x2buf (bf16), x_conv (bf16)
  pwfused_kernel<<<gemm_grid, blk, 0, stream>>>(
      x, w_pi, pib, w_cb1, cbb1, w_cb2, cbb2, x2buf, x_conv);
  // 2. dwbuf = dw_h(x2)
  dwh2_kernel<<<dim3(EL8), blk, 0, stream>>>(x2buf, hkdw, hkdb, dwbuf);
  // 3. attn_h = fsa_h(x2, tanh(hk_pw(dwbuf)))  — GEMM fused into fsa kernel
  fsahk_kernel<<<gemm_grid, blk, 0, stream>>>(
      dwbuf, x2buf, w_hk, hkpb, attn_h);
  // 4. dwbuf = dw_v(attn_h)
  dwv2_kernel<<<dim3(EL8), blk, 0, stream>>>(attn_h, vkdw, vkdb, dwbuf);
  // 5. attn = fsa_v(attn_h, tanh(vk_pw(dwbuf))) + at_mean partial sums
  fsavk_kernel<<<gemm_grid, blk, 0, stream>>>(
      dwbuf, attn_h, w_vk, vkpb, attn, at_mean);
  // 6-7. gating
  xs_kernel<<<dim3(PT, BATCH), blk, 0, stream>>>(x_conv, at_mean, xc_mean, s_sig);
  csig_kernel<<<dim3(BATCH * C2), blk, 0, stream>>>(attn, xc_mean, c_sig);
  // 8. out = proj_out([s_sig*xc ; c_sig*attn])  — concat fused into staging
  pw2_kernel<256, 256, 0, 1, bf16, float><<<gemm_grid, blk, 0, stream>>>(
      x_conv, 0, w_po, pob, out, DIM, x_conv, attn, s_sig, c_sig);
}